// Round 3
// baseline (2407.901 us; speedup 1.0000x reference)
//
#include <hip/hip_runtime.h>
#include <hip/hip_bf16.h>
#include <stdint.h>

// Problem constants (NicheST): N=4096, IN_DIM=3000, H1=512, D=64, K_sub=32, E=49152, HEADS=4
#define NN      4096
#define INDIM   3000
#define H1DIM   512
#define DDIM    64
#define RECON_ELEMS (NN * INDIM)

typedef __attribute__((ext_vector_type(8))) __bf16          bf16x8;
typedef __attribute__((ext_vector_type(8))) unsigned short  u16x8;
typedef __attribute__((ext_vector_type(4))) float           f32x4;

__device__ __forceinline__ unsigned short f2bf(float f) {
  union { float f; unsigned int i; } v; v.f = f;
  unsigned int x = v.i;
  unsigned int lsb = (x >> 16) & 1u;
  x += 0x7FFFu + lsb;                  // round-to-nearest-even
  return (unsigned short)(x >> 16);
}

// ---------------------------------------------------------------------------
// Threefry-2x32 (JAX-compatible, 20 rounds)
// ---------------------------------------------------------------------------
__device__ __forceinline__ void tf2x32(unsigned k0, unsigned k1, unsigned x0, unsigned x1,
                                       unsigned &o0, unsigned &o1) {
  unsigned ks2 = k0 ^ k1 ^ 0x1BD11BDAu;
  x0 += k0; x1 += k1;
#define TFR(r) { x0 += x1; x1 = (x1 << (r)) | (x1 >> (32 - (r))); x1 ^= x0; }
  TFR(13) TFR(15) TFR(26) TFR(6)
  x0 += k1; x1 += ks2 + 1u;
  TFR(17) TFR(29) TFR(16) TFR(24)
  x0 += ks2; x1 += k0 + 2u;
  TFR(13) TFR(15) TFR(26) TFR(6)
  x0 += k0; x1 += k1 + 3u;
  TFR(17) TFR(29) TFR(16) TFR(24)
  x0 += k1; x1 += ks2 + 4u;
  TFR(13) TFR(15) TFR(26) TFR(6)
  x0 += ks2; x1 += k0 + 5u;
#undef TFR
  o0 = x0; o1 = x1;
}

// ---------------------------------------------------------------------------
// Graph preprocessing
// ---------------------------------------------------------------------------
__global__ void k_deg(const int* __restrict__ dst, int* __restrict__ cnt, int E) {
  int e = blockIdx.x * 256 + threadIdx.x;
  if (e < E) atomicAdd(&cnt[dst[e]], 1);
}

__global__ void k_inv(const int* __restrict__ cnt, float* __restrict__ inv) {
  int n = blockIdx.x * 256 + threadIdx.x;
  if (n < NN) inv[n] = 1.0f / sqrtf((float)cnt[n] + 1.0f);
}

__global__ __launch_bounds__(1024) void k_scan(const int* __restrict__ cnt, int* __restrict__ offs) {
  __shared__ int ssum[1024];
  int tid = threadIdx.x;
  int c0 = cnt[tid*4], c1 = cnt[tid*4+1], c2 = cnt[tid*4+2], c3 = cnt[tid*4+3];
  int s = c0 + c1 + c2 + c3;
  ssum[tid] = s;
  __syncthreads();
  for (int off = 1; off < 1024; off <<= 1) {
    int v = (tid >= off) ? ssum[tid - off] : 0;
    __syncthreads();
    ssum[tid] += v;
    __syncthreads();
  }
  int base = ssum[tid] - s;  // exclusive prefix
  offs[tid*4]   = base;
  offs[tid*4+1] = base + c0;
  offs[tid*4+2] = base + c0 + c1;
  offs[tid*4+3] = base + c0 + c1 + c2;
  if (tid == 1023) offs[4096] = ssum[1023];
}

__global__ void k_scatter(const int* __restrict__ dst, const int* __restrict__ offs,
                          int* __restrict__ cur, int* __restrict__ eid, int E) {
  int e = blockIdx.x * 256 + threadIdx.x;
  if (e < E) {
    int d = dst[e];
    int pos = offs[d] + atomicAdd(&cur[d], 1);
    eid[pos] = e;
  }
}

// sort each node's edge list ascending by edge id -> deterministic accumulation
__global__ void k_sort(const int* __restrict__ offs, int* __restrict__ eid) {
  int n = blockIdx.x * 256 + threadIdx.x;
  if (n >= NN) return;
  int b = offs[n], e = offs[n+1];
  for (int i = b + 1; i < e; i++) {
    int v = eid[i]; int j = i - 1;
    while (j >= b && eid[j] > v) { eid[j+1] = eid[j]; j--; }
    eid[j+1] = v;
  }
}

// ---------------------------------------------------------------------------
// fp32 GEMM (conv1): C_z = x[4096,3000] @ w1[3000,512] over K-slice z.
// 128x128 tile, BK=16, 256 thr, 8x8/thread (2x2 blocks of 4x4). Split-K=2.
// ---------------------------------------------------------------------------
#define FBK 16
__global__ __launch_bounds__(256) void k_gemm_f32(
    const float* __restrict__ A, const float* __restrict__ B, float* __restrict__ C) {
  __shared__ float As[FBK * 132];
  __shared__ float Bs[FBK * 132];
  const int tid = threadIdx.x;
  const int m0 = blockIdx.y * 128;
  const int n0 = blockIdx.x * 128;
  const int z  = blockIdx.z;
  const int kBeg = z ? 1504 : 0;
  const int kEnd = z ? 3000 : 1504;
  C += (size_t)z * NN * 512;
  const int lane = tid & 63, w = tid >> 6;
  const int rg = w * 4 + (lane >> 4);  // 0..15 row group
  const int cg = lane & 15;            // 0..15 col group
  f32x4 acc[2][2][4];
#pragma unroll
  for (int a = 0; a < 2; a++)
#pragma unroll
    for (int b = 0; b < 2; b++)
#pragma unroll
      for (int i = 0; i < 4; i++) acc[a][b][i] = (f32x4){0.f,0.f,0.f,0.f};

  const int arow = tid & 127;
  const int asl  = tid >> 7;   // 0..1
  const int bkr  = tid >> 4;   // 0..15
  const int bcq  = tid & 15;   // 0..15

  for (int kt = kBeg; kt < kEnd; kt += FBK) {
    bool full = (kt + FBK <= kEnd);
    // stage A transposed: As[k][row]
#pragma unroll
    for (int it = 0; it < 2; it++) {
      int kk = (asl * 2 + it) * 4;
      f32x4 v;
      if (full) {
        v = *(const f32x4*)(A + (size_t)(m0 + arow) * INDIM + kt + kk);
      } else {
#pragma unroll
        for (int j = 0; j < 4; j++)
          v[j] = (kt + kk + j < kEnd) ? A[(size_t)(m0 + arow) * INDIM + kt + kk + j] : 0.f;
      }
      As[(kk+0)*132 + arow] = v[0];
      As[(kk+1)*132 + arow] = v[1];
      As[(kk+2)*132 + arow] = v[2];
      As[(kk+3)*132 + arow] = v[3];
    }
    // stage B: Bs[k][col]
    {
      f32x4 v0, v1;
      if (full || kt + bkr < kEnd) {
        const float* bp = B + (size_t)(kt + bkr) * 512 + n0 + bcq * 8;
        v0 = *(const f32x4*)bp;
        v1 = *(const f32x4*)(bp + 4);
      } else { v0 = (f32x4){0.f,0.f,0.f,0.f}; v1 = v0; }
      *(f32x4*)&Bs[bkr*132 + bcq*8]     = v0;
      *(f32x4*)&Bs[bkr*132 + bcq*8 + 4] = v1;
    }
    __syncthreads();
#pragma unroll
    for (int k = 0; k < FBK; k++) {
      f32x4 a0 = *(const f32x4*)&As[k*132 + rg*4];
      f32x4 a1 = *(const f32x4*)&As[k*132 + 64 + rg*4];
      f32x4 b0 = *(const f32x4*)&Bs[k*132 + cg*4];
      f32x4 b1 = *(const f32x4*)&Bs[k*132 + 64 + cg*4];
#pragma unroll
      for (int i = 0; i < 4; i++)
#pragma unroll
        for (int j = 0; j < 4; j++) {
          acc[0][0][i][j] = fmaf(a0[i], b0[j], acc[0][0][i][j]);
          acc[0][1][i][j] = fmaf(a0[i], b1[j], acc[0][1][i][j]);
          acc[1][0][i][j] = fmaf(a1[i], b0[j], acc[1][0][i][j]);
          acc[1][1][i][j] = fmaf(a1[i], b1[j], acc[1][1][i][j]);
        }
    }
    __syncthreads();
  }
#pragma unroll
  for (int a = 0; a < 2; a++)
#pragma unroll
    for (int i = 0; i < 4; i++) {
      int gr = m0 + a*64 + rg*4 + i;
#pragma unroll
      for (int b = 0; b < 2; b++)
        *(f32x4*)(C + (size_t)gr * 512 + n0 + b*64 + cg*4) = acc[a][b][i];
    }
}

// deterministic split-K combine: c0 += c1 (in place)
__global__ void k_combine(float* __restrict__ c0, const float* __restrict__ c1) {
  int i = blockIdx.x * 256 + threadIdx.x;
  ((f32x4*)c0)[i] = ((const f32x4*)c0)[i] + ((const f32x4*)c1)[i];
}

// ---------------------------------------------------------------------------
// bf16 MFMA GEMM (decoder): A bf16 [M,K], B f32 [K,N] converted on the fly.
// mode 1: +bias, ReLU, bf16 out. mode 2: +bias, f32 out.  K must be mult of 32.
// ---------------------------------------------------------------------------
__global__ __launch_bounds__(256) void k_gemm_bf(
    const unsigned short* __restrict__ A, const float* __restrict__ B,
    float* __restrict__ Cf, unsigned short* __restrict__ Cb,
    const float* __restrict__ bias,
    int M, int N, int K, int ldc, int mode) {
  __shared__ __attribute__((aligned(16))) unsigned short As[128 * 40];
  __shared__ __attribute__((aligned(16))) unsigned short Bs[128 * 40];
  const int tid  = threadIdx.x;
  const int m0   = blockIdx.y * 128;
  const int n0   = blockIdx.x * 128;
  const int lane = tid & 63;
  const int wid  = tid >> 6;
  const int wm   = wid >> 1, wn = wid & 1;
  const int lrow = lane & 15, lk = lane >> 4;

  f32x4 acc[4][4];
#pragma unroll
  for (int i = 0; i < 4; i++)
#pragma unroll
    for (int j = 0; j < 4; j++) acc[i][j] = (f32x4){0.f, 0.f, 0.f, 0.f};

  for (int k0 = 0; k0 < K; k0 += 32) {
    // stage A (already bf16)
#pragma unroll
    for (int it = 0; it < 2; it++) {
      int c   = it * 256 + tid;
      int row = c >> 2, kc = c & 3;
      int kg  = k0 + kc * 8;
      u16x8 v = *(const u16x8*)(A + (size_t)(m0 + row) * K + kg);
      *(u16x8*)&As[row * 40 + kc * 8] = v;
    }
    // stage B transposed, f32 -> bf16
    {
      int kk_ = tid & 31;
      int nc0 = tid >> 5;
      int kg  = k0 + kk_;
#pragma unroll
      for (int it = 0; it < 2; it++) {
        int nc = nc0 + it * 8;
        int ng = n0 + nc * 8;
        unsigned short vb[8];
        if (ng + 8 <= N) {
          f32x4 f0 = *(const f32x4*)(B + (size_t)kg * N + ng);
          f32x4 f1 = *(const f32x4*)(B + (size_t)kg * N + ng + 4);
#pragma unroll
          for (int j = 0; j < 4; j++) { vb[j] = f2bf(f0[j]); vb[4+j] = f2bf(f1[j]); }
        } else {
#pragma unroll
          for (int j = 0; j < 8; j++)
            vb[j] = (ng + j < N) ? f2bf(B[(size_t)kg * N + ng + j]) : (unsigned short)0;
        }
#pragma unroll
        for (int j = 0; j < 8; j++) Bs[(nc * 8 + j) * 40 + kk_] = vb[j];
      }
    }
    __syncthreads();
    bf16x8 af[4], bfr[4];
#pragma unroll
    for (int mi = 0; mi < 4; mi++) {
      u16x8 r = *(const u16x8*)&As[(wm * 64 + mi * 16 + lrow) * 40 + lk * 8];
      af[mi] = __builtin_bit_cast(bf16x8, r);
    }
#pragma unroll
    for (int ni = 0; ni < 4; ni++) {
      u16x8 r = *(const u16x8*)&Bs[(wn * 64 + ni * 16 + lrow) * 40 + lk * 8];
      bfr[ni] = __builtin_bit_cast(bf16x8, r);
    }
#pragma unroll
    for (int mi = 0; mi < 4; mi++)
#pragma unroll
      for (int ni = 0; ni < 4; ni++)
        acc[mi][ni] = __builtin_amdgcn_mfma_f32_16x16x32_bf16(af[mi], bfr[ni], acc[mi][ni], 0, 0, 0);
    __syncthreads();
  }

#pragma unroll
  for (int mi = 0; mi < 4; mi++)
#pragma unroll
    for (int ni = 0; ni < 4; ni++)
#pragma unroll
      for (int reg = 0; reg < 4; reg++) {
        int gr = m0 + wm * 64 + mi * 16 + lk * 4 + reg;
        int gc = n0 + wn * 64 + ni * 16 + lrow;
        if (gc < N) {
          float v = acc[mi][ni][reg] + bias[gc];
          if (mode == 1) {
            if (v < 0.f) v = 0.f;
            Cb[(size_t)gr * ldc + gc] = f2bf(v);
          } else {
            Cf[(size_t)gr * ldc + gc] = v;
          }
        }
      }
}

// ---------------------------------------------------------------------------
// GCN aggregation (deterministic edge order), f32
// ---------------------------------------------------------------------------
__global__ __launch_bounds__(256) void k_agg(
    const float* __restrict__ X, float* __restrict__ Y,
    const float* __restrict__ bias, const int* __restrict__ offs,
    const int* __restrict__ eid, const int* __restrict__ esrc,
    const float* __restrict__ inv, int F, int relu) {
  int n = blockIdx.x;
  int beg = offs[n], end = offs[n + 1];
  float invn = inv[n];
  float inv2 = invn * invn;
  for (int d = threadIdx.x; d < F; d += 256) {
    float acc = 0.f;
    for (int t = beg; t < end; t++) {
      int e = eid[t]; int s = esrc[e];
      float cf = inv[s] * invn;
      acc += X[(size_t)s * F + d] * cf;
    }
    acc += X[(size_t)n * F + d] * inv2;
    acc += bias[d];
    if (relu && acc < 0.f) acc = 0.f;
    Y[(size_t)n * F + d] = acc;
  }
}

// hw2[4096,64] = h[4096,512] @ enc_w2[512,64], all f32 (ranking path)
__global__ __launch_bounds__(256) void k_mmw2(const float* __restrict__ h,
                                              const float* __restrict__ w2,
                                              float* __restrict__ out) {
  __shared__ float hs[4 * 512];
  int tid  = threadIdx.x;
  int brow = blockIdx.x * 4;
  const f32x4* src = (const f32x4*)(h + (size_t)brow * 512);
  f32x4* dst4 = (f32x4*)hs;
  dst4[tid]       = src[tid];
  dst4[tid + 256] = src[tid + 256];
  __syncthreads();
  int r = tid >> 6, c = tid & 63;
  float acc = 0.f;
  const float* hr = hs + r * 512;
#pragma unroll 8
  for (int k = 0; k < 512; k++) acc = fmaf(hr[k], w2[k * 64 + c], acc);
  out[(size_t)(brow + r) * 64 + c] = acc;
}

// local[n] = mean over 32 sub_nodes of spot_emb (+ bf16 copy for decoder)
__global__ void k_pool(const float* __restrict__ spot, const int* __restrict__ sub,
                       float* __restrict__ local, unsigned short* __restrict__ local_bf) {
  int n = blockIdx.x, d = threadIdx.x;  // 64 threads
  float acc = 0.f;
  for (int j = 0; j < 32; j++) {
    int s = sub[n * 32 + j];
    acc += spot[(size_t)s * 64 + d];
  }
  float lv = acc * 0.03125f;
  local[(size_t)n * 64 + d] = lv;
  local_bf[(size_t)n * 64 + d] = f2bf(lv);
}

// qkv[n,192] = local[n] @ in_w^T + in_b   (f32)
__global__ void k_qkv(const float* __restrict__ local, const float* __restrict__ iw,
                      const float* __restrict__ ib, float* __restrict__ qkv) {
  __shared__ float lx[64];
  int n = blockIdx.x, t = threadIdx.x;  // 192 threads
  if (t < 64) lx[t] = local[(size_t)n * 64 + t];
  __syncthreads();
  float acc = 0.f;
#pragma unroll 8
  for (int d = 0; d < 64; d++) acc = fmaf(lx[d], iw[t * 64 + d], acc);
  qkv[(size_t)n * 192 + t] = acc + ib[t];
}

// ---------------------------------------------------------------------------
// Fused attention: per block AR=2 rows. Pass1 stats, pass2 avg row (LDS) + ctx,
// then in-block radix-select of the Threefry rank.
// ---------------------------------------------------------------------------
#define AR 2
__global__ __launch_bounds__(256) void k_attn(const float* __restrict__ qkv,
                                              float* __restrict__ ctx,
                                              int* __restrict__ sampled) {
  __shared__ float rowbuf[AR][4096];    // 32 KB: avg rows (pass1: reduction scratch)
  __shared__ float qsh[AR][64];
  __shared__ float osh[4][AR][64];
  __shared__ float sM[AR][4], sZ[AR][4];
  __shared__ unsigned hist[256];
  __shared__ unsigned sh_prefix;
  __shared__ int sh_r, sh_cnt;

  const int tid = threadIdx.x;
  const int n0 = blockIdx.x * AR;

  if (tid < AR * 64) qsh[tid >> 6][tid & 63] = qkv[(size_t)(n0 + (tid >> 6)) * 192 + (tid & 63)];
  __syncthreads();

  // ---- pass 1 ----
  float M[AR][4], Z[AR][4];
#pragma unroll
  for (int r = 0; r < AR; r++)
#pragma unroll
    for (int h = 0; h < 4; h++) { M[r][h] = -3.0e38f; Z[r][h] = 0.f; }

  for (int it = 0; it < 16; it++) {
    int m = it * 256 + tid;
    const f32x4* kp = (const f32x4*)(qkv + (size_t)m * 192 + 64);
    float s[AR][4];
#pragma unroll
    for (int r = 0; r < AR; r++)
#pragma unroll
      for (int h = 0; h < 4; h++) s[r][h] = 0.f;
#pragma unroll
    for (int c4 = 0; c4 < 16; c4++) {
      f32x4 kv = kp[c4];
      int h = c4 >> 2;
#pragma unroll
      for (int r = 0; r < AR; r++) {
        s[r][h] = fmaf(qsh[r][4*c4+0], kv[0], s[r][h]);
        s[r][h] = fmaf(qsh[r][4*c4+1], kv[1], s[r][h]);
        s[r][h] = fmaf(qsh[r][4*c4+2], kv[2], s[r][h]);
        s[r][h] = fmaf(qsh[r][4*c4+3], kv[3], s[r][h]);
      }
    }
#pragma unroll
    for (int r = 0; r < AR; r++)
#pragma unroll
      for (int h = 0; h < 4; h++) {
        float sv = s[r][h] * 0.25f;
        if (sv > M[r][h]) { Z[r][h] = fmaf(Z[r][h], expf(M[r][h] - sv), 1.0f); M[r][h] = sv; }
        else               Z[r][h] += expf(sv - M[r][h]);
      }
  }
#pragma unroll
  for (int r = 0; r < AR; r++)
#pragma unroll
    for (int h = 0; h < 4; h++) {
      rowbuf[0][(r*4+h)*256 + tid] = M[r][h];
      rowbuf[1][(r*4+h)*256 + tid] = Z[r][h];
    }
  __syncthreads();
  if (tid < AR*4) {
    const float* pm = &rowbuf[0][tid*256];
    const float* pz = &rowbuf[1][tid*256];
    float Mv = -3.0e38f, Zv = 0.f;
    for (int i = 0; i < 256; i++) {
      float m_ = pm[i], z_ = pz[i];
      if (m_ > Mv) { Zv = fmaf(Zv, expf(Mv - m_), z_); Mv = m_; }
      else         Zv = fmaf(z_, expf(m_ - Mv), Zv);
    }
    sM[tid>>2][tid&3] = Mv;
    sZ[tid>>2][tid&3] = Zv;
  }
  __syncthreads();

  float Mh[AR][4], iZ[AR][4];
#pragma unroll
  for (int r = 0; r < AR; r++)
#pragma unroll
    for (int h = 0; h < 4; h++) { Mh[r][h] = sM[r][h]; iZ[r][h] = 1.0f / sZ[r][h]; }
  __syncthreads();

  // ---- pass 2 ----
  float o[AR][64];
#pragma unroll
  for (int r = 0; r < AR; r++)
#pragma unroll
    for (int d = 0; d < 64; d++) o[r][d] = 0.f;

  for (int it = 0; it < 16; it++) {
    int m = it * 256 + tid;
    const f32x4* kp = (const f32x4*)(qkv + (size_t)m * 192 + 64);
    float s[AR][4];
#pragma unroll
    for (int r = 0; r < AR; r++)
#pragma unroll
      for (int h = 0; h < 4; h++) s[r][h] = 0.f;
#pragma unroll
    for (int c4 = 0; c4 < 16; c4++) {
      f32x4 kv = kp[c4];
      int h = c4 >> 2;
#pragma unroll
      for (int r = 0; r < AR; r++) {
        s[r][h] = fmaf(qsh[r][4*c4+0], kv[0], s[r][h]);
        s[r][h] = fmaf(qsh[r][4*c4+1], kv[1], s[r][h]);
        s[r][h] = fmaf(qsh[r][4*c4+2], kv[2], s[r][h]);
        s[r][h] = fmaf(qsh[r][4*c4+3], kv[3], s[r][h]);
      }
    }
    float p[AR][4];
#pragma unroll
    for (int r = 0; r < AR; r++)
#pragma unroll
      for (int h = 0; h < 4; h++)
        p[r][h] = expf(s[r][h] * 0.25f - Mh[r][h]) * iZ[r][h];
#pragma unroll
    for (int r = 0; r < AR; r++)
      rowbuf[r][m] = (((p[r][0] + p[r][1]) + p[r][2]) + p[r][3]) * 0.25f;
    const f32x4* vp = (const f32x4*)(qkv + (size_t)m * 192 + 128);
#pragma unroll
    for (int c4 = 0; c4 < 16; c4++) {
      f32x4 vv = vp[c4];
      int h = c4 >> 2;
#pragma unroll
      for (int r = 0; r < AR; r++) {
        o[r][4*c4+0] = fmaf(p[r][h], vv[0], o[r][4*c4+0]);
        o[r][4*c4+1] = fmaf(p[r][h], vv[1], o[r][4*c4+1]);
        o[r][4*c4+2] = fmaf(p[r][h], vv[2], o[r][4*c4+2]);
        o[r][4*c4+3] = fmaf(p[r][h], vv[3], o[r][4*c4+3]);
      }
    }
  }
  // deterministic reduction: wave butterfly -> per-wave LDS partials -> sum of 4
  {
    int w = tid >> 6;
#pragma unroll
    for (int r = 0; r < AR; r++)
#pragma unroll
      for (int d = 0; d < 64; d++) {
        float v = o[r][d];
        for (int mask = 1; mask < 64; mask <<= 1) v += __shfl_xor(v, mask, 64);
        if ((tid & 63) == d) osh[w][r][d] = v;
      }
  }
  __syncthreads();
  if (tid < AR * 64) {
    int r = tid >> 6, d = tid & 63;
    ctx[(size_t)(n0 + r) * 64 + d] =
        ((osh[0][r][d] + osh[1][r][d]) + osh[2][r][d]) + osh[3][r][d];
  }
  __syncthreads();

  // ---- per-row radix select (Threefry rank; ties -> lowest index) ----
  for (int rr = 0; rr < AR; rr++) {
    int n = n0 + rr;
    if (tid == 0) {
      // k1,k2 = split(key(42)): counts iota(4) -> pairs (0,2),(1,3); k2 = (o1(0,2), o1(1,3))
      unsigned a0, a1, b0, b1;
      tf2x32(0u, 42u, 0u, 2u, a0, a1);
      tf2x32(0u, 42u, 1u, 3u, b0, b1);
      // bits = threefry(k2, iota(4096)): pairs (n, n+2048)
      unsigned o0, o1, bits;
      if (n < 2048) { tf2x32(a1, b1, (unsigned)n, (unsigned)(n + 2048), o0, o1); bits = o0; }
      else          { tf2x32(a1, b1, (unsigned)(n - 2048), (unsigned)n, o0, o1); bits = o1; }
      sh_r = (int)(bits & 1023u);   // randint(0,1024): pow2 span -> lower_bits % 1024
      sh_prefix = 0u;
    }
    __syncthreads();
    int r = sh_r;
    unsigned prefix = 0u;
    int cnt_eq = 0;
    const float* row = rowbuf[rr];
    for (int level = 0; level < 4; level++) {
      int shift = 24 - 8 * level;
      hist[tid] = 0u;
      __syncthreads();
      for (int i = tid; i < 4096; i += 256) {
        unsigned u = __float_as_uint(row[i]);
        bool ok = (level == 0) || ((u >> (shift + 8)) == (prefix >> (shift + 8)));
        if (ok) atomicAdd(&hist[(u >> shift) & 255u], 1u);
      }
      __syncthreads();
      for (int off = 1; off < 256; off <<= 1) {
        unsigned v = (tid >= off) ? hist[tid - off] : 0u;
        __syncthreads();
        hist[tid] += v;
        __syncthreads();
      }
      unsigned cb = (tid > 0) ? hist[tid - 1] : 0u;
      unsigned ci = hist[tid];
      if ((unsigned)r >= cb && (unsigned)r < ci) {
        sh_prefix = prefix | ((unsigned)tid << shift);
        sh_r = r - (int)cb;
        sh_cnt = (int)(ci - cb);
      }
      __syncthreads();
      prefix = sh_prefix; r = sh_r; cnt_eq = sh_cnt;
      __syncthreads();
    }
    if (cnt_eq == 1) {
      for (int i = tid; i < 4096; i += 256)
        if (__float_as_uint(row[i]) == prefix) sampled[n] = i;
    } else if (tid == 0) {
      int c = 0;
      for (int i = 0; i < 4096; i++)
        if (__float_as_uint(row[i]) == prefix) { if (c == r) { sampled[n] = i; break; } c++; }
    }
    __syncthreads();
  }
}

// global_niches = ctx @ out_w^T + out_b  (f32)
__global__ void k_outproj(const float* __restrict__ ctx, const float* __restrict__ ow,
                          const float* __restrict__ ob, float* __restrict__ gni) {
  __shared__ float cx[64];
  int n = blockIdx.x, t = threadIdx.x;  // 64 threads
  cx[t] = ctx[(size_t)n * 64 + t];
  __syncthreads();
  float acc = 0.f;
#pragma unroll 8
  for (int j = 0; j < 64; j++) acc = fmaf(cx[j], ow[t * 64 + j], acc);
  gni[(size_t)n * 64 + t] = acc + ob[t];
}

// bilinear discriminator logits (pos & neg), f32 outputs
__global__ void k_logits(const float* __restrict__ local, const float* __restrict__ gni,
                         const int* __restrict__ sampled,
                         const float* __restrict__ bw, const float* __restrict__ bb,
                         float* __restrict__ outp, float* __restrict__ outn) {
  __shared__ float lv[64], gp[64], gn[64];
  int n = blockIdx.x, t = threadIdx.x;  // 64 threads
  int sm = sampled[n];
  lv[t] = local[(size_t)n * 64 + t];
  gp[t] = gni[(size_t)n * 64 + t];
  gn[t] = gni[(size_t)sm * 64 + t];
  __syncthreads();
  float tp = 0.f, tn = 0.f;
#pragma unroll 8
  for (int e = 0; e < 64; e++) {
    float w = bw[t * 64 + e];
    tp = fmaf(w, gp[e], tp);
    tn = fmaf(w, gn[e], tn);
  }
  float vp = lv[t] * tp, vn = lv[t] * tn;
  for (int off = 32; off; off >>= 1) {
    vp += __shfl_down(vp, off, 64);
    vn += __shfl_down(vn, off, 64);
  }
  if (t == 0) {
    outp[n] = vp + bb[0];
    outn[n] = vn + bb[0];
  }
}

// ---------------------------------------------------------------------------
extern "C" void kernel_launch(void* const* d_in, const int* in_sizes, int n_in,
                              void* d_out, int out_size, void* d_ws, size_t ws_size,
                              hipStream_t stream) {
  const float* x      = (const float*)d_in[0];
  const int*   edge   = (const int*)d_in[1];
  const int*   sub    = (const int*)d_in[2];
  const float* enc_w1 = (const float*)d_in[3];
  const float* enc_b1 = (const float*)d_in[4];
  const float* enc_w2 = (const float*)d_in[5];
  const float* enc_b2 = (const float*)d_in[6];
  const float* dec_w1 = (const float*)d_in[7];
  const float* dec_b1 = (const float*)d_in[8];
  const float* dec_w2 = (const float*)d_in[9];
  const float* dec_b2 = (const float*)d_in[10];
  const float* ain_w  = (const float*)d_in[11];
  const float* ain_b  = (const float*)d_in[12];
  const float* aout_w = (const float*)d_in[13];
  const float* aout_b = (const float*)d_in[14];
  const float* bil_w  = (const float*)d_in[15];
  const float* bil_b  = (const float*)d_in[16];
  float* out = (float*)d_out;

  const int E = in_sizes[1] / 2;  // 49152
  const int* esrc = edge;
  const int* edst = edge + E;

  // ---- time-overlapped workspace (~19.8 MB) ----
  char* base = (char*)d_ws;
  const size_t MB = (size_t)1 << 20;
  float*          cpart    = (float*)(base + 0);             // [conv1..combine] 16MB (2 x 8MB)
  float*          h_pre    = (float*)(base + 0);             // = cpart slice 0, [combine..agg1]
  unsigned short* dech_bf  = (unsigned short*)(base + 0);    // [dec1..dec2] 4MB
  float*          h        = (float*)(base + 8*MB);          // [agg1..mmw2] 8MB
  float*          qkv      = (float*)(base + 8*MB);          // [qkv..attn] 3MB
  float*          ctx      = (float*)(base + 11*MB);         // [attn..outproj] 1MB
  float*          gni      = (float*)(base + 12*MB);         // [outproj..logits] 1MB
  float*          hw2      = (float*)(base + 16*MB);         // [mmw2..agg2] 1MB
  float*          spot     = (float*)(base + 17*MB);         // [agg2..pool] 1MB
  float*          localf   = (float*)(base + 18*MB);         // [pool..logits] 1MB
  unsigned short* local_bf = (unsigned short*)(base + 19*MB);// [pool..dec1] 0.5MB
  char* ip = base + 19*MB + 512*1024;
  float* inv    = (float*)ip;  ip += 16384;
  int*   degcnt = (int*)ip;    ip += 16384;  // zeroed
  int*   cursor = (int*)ip;    ip += 16384;  // zeroed
  int*   offs   = (int*)ip;    ip += 16640;
  int*   sampled= (int*)ip;    ip += 16384;
  int*   eid    = (int*)ip;    ip += (size_t)E * 4;

  hipMemsetAsync(degcnt, 0, (size_t)NN * 4, stream);
  hipMemsetAsync(cursor, 0, (size_t)NN * 4, stream);

  int egrid = (E + 255) / 256;
  k_deg<<<egrid, 256, 0, stream>>>(edst, degcnt, E);
  k_inv<<<(NN + 255) / 256, 256, 0, stream>>>(degcnt, inv);
  k_scan<<<1, 1024, 0, stream>>>(degcnt, offs);
  k_scatter<<<egrid, 256, 0, stream>>>(edst, offs, cursor, eid, E);
  k_sort<<<(NN + 255) / 256, 256, 0, stream>>>(offs, eid);

  // encoder conv1: f32, split-K=2 + deterministic combine
  {
    dim3 g(4, 32, 2);
    k_gemm_f32<<<g, 256, 0, stream>>>(x, enc_w1, cpart);
  }
  k_combine<<<(NN * 512 / 4) / 256, 256, 0, stream>>>(h_pre, cpart + (size_t)NN * 512);
  k_agg<<<NN, 256, 0, stream>>>(h_pre, h, enc_b1, offs, eid, esrc, inv, 512, 1);
  k_mmw2<<<NN / 4, 256, 0, stream>>>(h, enc_w2, hw2);
  k_agg<<<NN, 256, 0, stream>>>(hw2, spot, enc_b2, offs, eid, esrc, inv, 64, 0);
  k_pool<<<NN, 64, 0, stream>>>(spot, sub, localf, local_bf);

  // decoder (bf16 MFMA, f32 weights converted on the fly)
  {
    dim3 g(4, 32);
    k_gemm_bf<<<g, 256, 0, stream>>>(local_bf, dec_w1, nullptr, dech_bf, dec_b1,
                                     NN, 512, 64, 512, 1);
  }
  {
    dim3 g(24, 32);
    k_gemm_bf<<<g, 256, 0, stream>>>(dech_bf, dec_w2, out, nullptr, dec_b2,
                                     NN, INDIM, 512, INDIM, 2);
  }

  // attention (f32 ranking path, fused stats+avg+ctx+select)
  k_qkv<<<NN, 192, 0, stream>>>(localf, ain_w, ain_b, qkv);
  k_attn<<<NN / AR, 256, 0, stream>>>(qkv, ctx, sampled);
  k_outproj<<<NN, 64, 0, stream>>>(ctx, aout_w, aout_b, gni);
  k_logits<<<NN, 64, 0, stream>>>(localf, gni, sampled, bil_w, bil_b,
                                  out + RECON_ELEMS, out + RECON_ELEMS + NN);
}

// Round 4
// 1470.538 us; speedup vs baseline: 1.6374x; 1.6374x over previous
//
#include <hip/hip_runtime.h>
#include <hip/hip_bf16.h>
#include <stdint.h>

// Problem constants (NicheST): N=4096, IN_DIM=3000, H1=512, D=64, K_sub=32, E=49152, HEADS=4
#define NN      4096
#define INDIM   3000
#define H1DIM   512
#define DDIM    64
#define RECON_ELEMS (NN * INDIM)

typedef __attribute__((ext_vector_type(8))) __bf16          bf16x8;
typedef __attribute__((ext_vector_type(8))) unsigned short  u16x8;
typedef __attribute__((ext_vector_type(4))) float           f32x4;

__device__ __forceinline__ unsigned short f2bf(float f) {
  union { float f; unsigned int i; } v; v.f = f;
  unsigned int x = v.i;
  unsigned int lsb = (x >> 16) & 1u;
  x += 0x7FFFu + lsb;                  // round-to-nearest-even
  return (unsigned short)(x >> 16);
}

// ---------------------------------------------------------------------------
// Threefry-2x32 (JAX-compatible, 20 rounds)
// ---------------------------------------------------------------------------
__device__ __forceinline__ void tf2x32(unsigned k0, unsigned k1, unsigned x0, unsigned x1,
                                       unsigned &o0, unsigned &o1) {
  unsigned ks2 = k0 ^ k1 ^ 0x1BD11BDAu;
  x0 += k0; x1 += k1;
#define TFR(r) { x0 += x1; x1 = (x1 << (r)) | (x1 >> (32 - (r))); x1 ^= x0; }
  TFR(13) TFR(15) TFR(26) TFR(6)
  x0 += k1; x1 += ks2 + 1u;
  TFR(17) TFR(29) TFR(16) TFR(24)
  x0 += ks2; x1 += k0 + 2u;
  TFR(13) TFR(15) TFR(26) TFR(6)
  x0 += k0; x1 += k1 + 3u;
  TFR(17) TFR(29) TFR(16) TFR(24)
  x0 += k1; x1 += ks2 + 4u;
  TFR(13) TFR(15) TFR(26) TFR(6)
  x0 += ks2; x1 += k0 + 5u;
#undef TFR
  o0 = x0; o1 = x1;
}

// ---------------------------------------------------------------------------
// Graph preprocessing
// ---------------------------------------------------------------------------
__global__ void k_deg(const int* __restrict__ dst, int* __restrict__ cnt, int E) {
  int e = blockIdx.x * 256 + threadIdx.x;
  if (e < E) atomicAdd(&cnt[dst[e]], 1);
}

__global__ void k_inv(const int* __restrict__ cnt, float* __restrict__ inv) {
  int n = blockIdx.x * 256 + threadIdx.x;
  if (n < NN) inv[n] = 1.0f / sqrtf((float)cnt[n] + 1.0f);
}

__global__ __launch_bounds__(1024) void k_scan(const int* __restrict__ cnt, int* __restrict__ offs) {
  __shared__ int ssum[1024];
  int tid = threadIdx.x;
  int c0 = cnt[tid*4], c1 = cnt[tid*4+1], c2 = cnt[tid*4+2], c3 = cnt[tid*4+3];
  int s = c0 + c1 + c2 + c3;
  ssum[tid] = s;
  __syncthreads();
  for (int off = 1; off < 1024; off <<= 1) {
    int v = (tid >= off) ? ssum[tid - off] : 0;
    __syncthreads();
    ssum[tid] += v;
    __syncthreads();
  }
  int base = ssum[tid] - s;  // exclusive prefix
  offs[tid*4]   = base;
  offs[tid*4+1] = base + c0;
  offs[tid*4+2] = base + c0 + c1;
  offs[tid*4+3] = base + c0 + c1 + c2;
  if (tid == 1023) offs[4096] = ssum[1023];
}

__global__ void k_scatter(const int* __restrict__ dst, const int* __restrict__ offs,
                          int* __restrict__ cur, int* __restrict__ eid, int E) {
  int e = blockIdx.x * 256 + threadIdx.x;
  if (e < E) {
    int d = dst[e];
    int pos = offs[d] + atomicAdd(&cur[d], 1);
    eid[pos] = e;
  }
}

// sort each node's edge list ascending by edge id -> deterministic accumulation
__global__ void k_sort(const int* __restrict__ offs, int* __restrict__ eid) {
  int n = blockIdx.x * 256 + threadIdx.x;
  if (n >= NN) return;
  int b = offs[n], e = offs[n+1];
  for (int i = b + 1; i < e; i++) {
    int v = eid[i]; int j = i - 1;
    while (j >= b && eid[j] > v) { eid[j+1] = eid[j]; j--; }
    eid[j+1] = v;
  }
}

// ---------------------------------------------------------------------------
// fp32 GEMM (conv1): C_z = x[4096,3000] @ w1[3000,512] over K-slice z.
// 128x128 tile, BK=16, 256 thr, 8x8/thread (2x2 blocks of 4x4). Split-K=2.
// ---------------------------------------------------------------------------
#define FBK 16
__global__ __launch_bounds__(256) void k_gemm_f32(
    const float* __restrict__ A, const float* __restrict__ B, float* __restrict__ C) {
  __shared__ float As[FBK * 132];
  __shared__ float Bs[FBK * 132];
  const int tid = threadIdx.x;
  const int m0 = blockIdx.y * 128;
  const int n0 = blockIdx.x * 128;
  const int z  = blockIdx.z;
  const int kBeg = z ? 1504 : 0;
  const int kEnd = z ? 3000 : 1504;
  C += (size_t)z * NN * 512;
  const int lane = tid & 63, w = tid >> 6;
  const int rg = w * 4 + (lane >> 4);  // 0..15 row group
  const int cg = lane & 15;            // 0..15 col group
  f32x4 acc[2][2][4];
#pragma unroll
  for (int a = 0; a < 2; a++)
#pragma unroll
    for (int b = 0; b < 2; b++)
#pragma unroll
      for (int i = 0; i < 4; i++) acc[a][b][i] = (f32x4){0.f,0.f,0.f,0.f};

  const int arow = tid & 127;
  const int asl  = tid >> 7;   // 0..1
  const int bkr  = tid >> 4;   // 0..15
  const int bcq  = tid & 15;   // 0..15

  for (int kt = kBeg; kt < kEnd; kt += FBK) {
    bool full = (kt + FBK <= kEnd);
    // stage A transposed: As[k][row]
#pragma unroll
    for (int it = 0; it < 2; it++) {
      int kk = (asl * 2 + it) * 4;
      f32x4 v;
      if (full) {
        v = *(const f32x4*)(A + (size_t)(m0 + arow) * INDIM + kt + kk);
      } else {
#pragma unroll
        for (int j = 0; j < 4; j++)
          v[j] = (kt + kk + j < kEnd) ? A[(size_t)(m0 + arow) * INDIM + kt + kk + j] : 0.f;
      }
      As[(kk+0)*132 + arow] = v[0];
      As[(kk+1)*132 + arow] = v[1];
      As[(kk+2)*132 + arow] = v[2];
      As[(kk+3)*132 + arow] = v[3];
    }
    // stage B: Bs[k][col]
    {
      f32x4 v0, v1;
      if (full || kt + bkr < kEnd) {
        const float* bp = B + (size_t)(kt + bkr) * 512 + n0 + bcq * 8;
        v0 = *(const f32x4*)bp;
        v1 = *(const f32x4*)(bp + 4);
      } else { v0 = (f32x4){0.f,0.f,0.f,0.f}; v1 = v0; }
      *(f32x4*)&Bs[bkr*132 + bcq*8]     = v0;
      *(f32x4*)&Bs[bkr*132 + bcq*8 + 4] = v1;
    }
    __syncthreads();
#pragma unroll
    for (int k = 0; k < FBK; k++) {
      f32x4 a0 = *(const f32x4*)&As[k*132 + rg*4];
      f32x4 a1 = *(const f32x4*)&As[k*132 + 64 + rg*4];
      f32x4 b0 = *(const f32x4*)&Bs[k*132 + cg*4];
      f32x4 b1 = *(const f32x4*)&Bs[k*132 + 64 + cg*4];
#pragma unroll
      for (int i = 0; i < 4; i++)
#pragma unroll
        for (int j = 0; j < 4; j++) {
          acc[0][0][i][j] = fmaf(a0[i], b0[j], acc[0][0][i][j]);
          acc[0][1][i][j] = fmaf(a0[i], b1[j], acc[0][1][i][j]);
          acc[1][0][i][j] = fmaf(a1[i], b0[j], acc[1][0][i][j]);
          acc[1][1][i][j] = fmaf(a1[i], b1[j], acc[1][1][i][j]);
        }
    }
    __syncthreads();
  }
#pragma unroll
  for (int a = 0; a < 2; a++)
#pragma unroll
    for (int i = 0; i < 4; i++) {
      int gr = m0 + a*64 + rg*4 + i;
#pragma unroll
      for (int b = 0; b < 2; b++)
        *(f32x4*)(C + (size_t)gr * 512 + n0 + b*64 + cg*4) = acc[a][b][i];
    }
}

// deterministic split-K combine: c0 += c1 (in place)
__global__ void k_combine(float* __restrict__ c0, const float* __restrict__ c1) {
  int i = blockIdx.x * 256 + threadIdx.x;
  ((f32x4*)c0)[i] = ((const f32x4*)c0)[i] + ((const f32x4*)c1)[i];
}

// ---------------------------------------------------------------------------
// bf16 MFMA GEMM (decoder): A bf16 [M,K], B f32 [K,N] converted on the fly.
// mode 1: +bias, ReLU, bf16 out. mode 2: +bias, f32 out.  K must be mult of 32.
// ---------------------------------------------------------------------------
__global__ __launch_bounds__(256) void k_gemm_bf(
    const unsigned short* __restrict__ A, const float* __restrict__ B,
    float* __restrict__ Cf, unsigned short* __restrict__ Cb,
    const float* __restrict__ bias,
    int M, int N, int K, int ldc, int mode) {
  __shared__ __attribute__((aligned(16))) unsigned short As[128 * 40];
  __shared__ __attribute__((aligned(16))) unsigned short Bs[128 * 40];
  const int tid  = threadIdx.x;
  const int m0   = blockIdx.y * 128;
  const int n0   = blockIdx.x * 128;
  const int lane = tid & 63;
  const int wid  = tid >> 6;
  const int wm   = wid >> 1, wn = wid & 1;
  const int lrow = lane & 15, lk = lane >> 4;

  f32x4 acc[4][4];
#pragma unroll
  for (int i = 0; i < 4; i++)
#pragma unroll
    for (int j = 0; j < 4; j++) acc[i][j] = (f32x4){0.f, 0.f, 0.f, 0.f};

  for (int k0 = 0; k0 < K; k0 += 32) {
    // stage A (already bf16)
#pragma unroll
    for (int it = 0; it < 2; it++) {
      int c   = it * 256 + tid;
      int row = c >> 2, kc = c & 3;
      int kg  = k0 + kc * 8;
      u16x8 v = *(const u16x8*)(A + (size_t)(m0 + row) * K + kg);
      *(u16x8*)&As[row * 40 + kc * 8] = v;
    }
    // stage B transposed, f32 -> bf16
    {
      int kk_ = tid & 31;
      int nc0 = tid >> 5;
      int kg  = k0 + kk_;
#pragma unroll
      for (int it = 0; it < 2; it++) {
        int nc = nc0 + it * 8;
        int ng = n0 + nc * 8;
        unsigned short vb[8];
        if (ng + 8 <= N) {
          f32x4 f0 = *(const f32x4*)(B + (size_t)kg * N + ng);
          f32x4 f1 = *(const f32x4*)(B + (size_t)kg * N + ng + 4);
#pragma unroll
          for (int j = 0; j < 4; j++) { vb[j] = f2bf(f0[j]); vb[4+j] = f2bf(f1[j]); }
        } else {
#pragma unroll
          for (int j = 0; j < 8; j++)
            vb[j] = (ng + j < N) ? f2bf(B[(size_t)kg * N + ng + j]) : (unsigned short)0;
        }
#pragma unroll
        for (int j = 0; j < 8; j++) Bs[(nc * 8 + j) * 40 + kk_] = vb[j];
      }
    }
    __syncthreads();
    bf16x8 af[4], bfr[4];
#pragma unroll
    for (int mi = 0; mi < 4; mi++) {
      u16x8 r = *(const u16x8*)&As[(wm * 64 + mi * 16 + lrow) * 40 + lk * 8];
      af[mi] = __builtin_bit_cast(bf16x8, r);
    }
#pragma unroll
    for (int ni = 0; ni < 4; ni++) {
      u16x8 r = *(const u16x8*)&Bs[(wn * 64 + ni * 16 + lrow) * 40 + lk * 8];
      bfr[ni] = __builtin_bit_cast(bf16x8, r);
    }
#pragma unroll
    for (int mi = 0; mi < 4; mi++)
#pragma unroll
      for (int ni = 0; ni < 4; ni++)
        acc[mi][ni] = __builtin_amdgcn_mfma_f32_16x16x32_bf16(af[mi], bfr[ni], acc[mi][ni], 0, 0, 0);
    __syncthreads();
  }

#pragma unroll
  for (int mi = 0; mi < 4; mi++)
#pragma unroll
    for (int ni = 0; ni < 4; ni++)
#pragma unroll
      for (int reg = 0; reg < 4; reg++) {
        int gr = m0 + wm * 64 + mi * 16 + lk * 4 + reg;
        int gc = n0 + wn * 64 + ni * 16 + lrow;
        if (gc < N) {
          float v = acc[mi][ni][reg] + bias[gc];
          if (mode == 1) {
            if (v < 0.f) v = 0.f;
            Cb[(size_t)gr * ldc + gc] = f2bf(v);
          } else {
            Cf[(size_t)gr * ldc + gc] = v;
          }
        }
      }
}

// ---------------------------------------------------------------------------
// GCN aggregation (deterministic edge order), f32
// ---------------------------------------------------------------------------
__global__ __launch_bounds__(256) void k_agg(
    const float* __restrict__ X, float* __restrict__ Y,
    const float* __restrict__ bias, const int* __restrict__ offs,
    const int* __restrict__ eid, const int* __restrict__ esrc,
    const float* __restrict__ inv, int F, int relu) {
  int n = blockIdx.x;
  int beg = offs[n], end = offs[n + 1];
  float invn = inv[n];
  float inv2 = invn * invn;
  for (int d = threadIdx.x; d < F; d += 256) {
    float acc = 0.f;
    for (int t = beg; t < end; t++) {
      int e = eid[t]; int s = esrc[e];
      float cf = inv[s] * invn;
      acc += X[(size_t)s * F + d] * cf;
    }
    acc += X[(size_t)n * F + d] * inv2;
    acc += bias[d];
    if (relu && acc < 0.f) acc = 0.f;
    Y[(size_t)n * F + d] = acc;
  }
}

// hw2[4096,64] = h[4096,512] @ enc_w2[512,64], all f32 (ranking path)
__global__ __launch_bounds__(256) void k_mmw2(const float* __restrict__ h,
                                              const float* __restrict__ w2,
                                              float* __restrict__ out) {
  __shared__ float hs[4 * 512];
  int tid  = threadIdx.x;
  int brow = blockIdx.x * 4;
  const f32x4* src = (const f32x4*)(h + (size_t)brow * 512);
  f32x4* dst4 = (f32x4*)hs;
  dst4[tid]       = src[tid];
  dst4[tid + 256] = src[tid + 256];
  __syncthreads();
  int r = tid >> 6, c = tid & 63;
  float acc = 0.f;
  const float* hr = hs + r * 512;
#pragma unroll 8
  for (int k = 0; k < 512; k++) acc = fmaf(hr[k], w2[k * 64 + c], acc);
  out[(size_t)(brow + r) * 64 + c] = acc;
}

// local[n] = mean over 32 sub_nodes of spot_emb (+ bf16 copy for decoder)
__global__ void k_pool(const float* __restrict__ spot, const int* __restrict__ sub,
                       float* __restrict__ local, unsigned short* __restrict__ local_bf) {
  int n = blockIdx.x, d = threadIdx.x;  // 64 threads
  float acc = 0.f;
  for (int j = 0; j < 32; j++) {
    int s = sub[n * 32 + j];
    acc += spot[(size_t)s * 64 + d];
  }
  float lv = acc * 0.03125f;
  local[(size_t)n * 64 + d] = lv;
  local_bf[(size_t)n * 64 + d] = f2bf(lv);
}

// Q/K/V packed rows: Qp/Kp/Vp[n][64] = local[n] @ in_w^T + in_b (f32)
__global__ void k_qkv(const float* __restrict__ local, const float* __restrict__ iw,
                      const float* __restrict__ ib,
                      float* __restrict__ Qp, float* __restrict__ Kp, float* __restrict__ Vp) {
  __shared__ float lx[64];
  int n = blockIdx.x, t = threadIdx.x;  // 192 threads
  if (t < 64) lx[t] = local[(size_t)n * 64 + t];
  __syncthreads();
  float acc = 0.f;
#pragma unroll 8
  for (int d = 0; d < 64; d++) acc = fmaf(lx[d], iw[t * 64 + d], acc);
  acc += ib[t];
  if (t < 64)       Qp[(size_t)n * 64 + t] = acc;
  else if (t < 128) Kp[(size_t)n * 64 + (t - 64)] = acc;
  else              Vp[(size_t)n * 64 + (t - 128)] = acc;
}

// ---------------------------------------------------------------------------
// Fused attention v2: 1024 blocks x 4 q-rows, m-tiles of 64 staged in LDS.
// Score role: thread = (m, q-pair, h-pair), Q in regs, swizzled K b128 reads.
// PV role: thread = (d-quad, m-slice), P via padded LDS tile. Deterministic.
// Selection: per-row radix select on LDS rowbuf (vals kept per-thread).
// ---------------------------------------------------------------------------
#define MT 64
#define RT 4
__global__ __launch_bounds__(256, 2) void k_attn(
    const float* __restrict__ Qp, const float* __restrict__ Kp, const float* __restrict__ Vp,
    float* __restrict__ ctx, int* __restrict__ sampled) {
  __shared__ __attribute__((aligned(16))) float Kt[MT * 16 * 4];   // swizzled [m][sc][4], 16 KB (alias: Osh)
  __shared__ __attribute__((aligned(16))) float VT[16 * 65 * 4];   // [dq][m pad65][4], 16.6 KB (alias: redM/Z, rowbuf)
  __shared__ __attribute__((aligned(16))) float Pt[16 * 68];       // [q*4+h][m pad68], 4.3 KB
  __shared__ float qs[RT * 64];
  __shared__ float sMZ[2][4][4];
  __shared__ unsigned hist[256];
  __shared__ unsigned sh_prefix;
  __shared__ int sh_r, sh_cnt;

  const int t  = threadIdx.x;
  const int n0 = blockIdx.x * RT;
  const int sm  = t & 63;          // score role: m in tile
  const int sqp = (t >> 6) & 1;    // q-pair
  const int shp = t >> 7;          // h-pair (d-half)
  const int q_v = sqp * 2 + shp;   // the q-row whose avg this thread records
  const int dq  = t & 15;          // PV role: d-quad
  const int me  = t >> 4;          // PV role: m-slice (4 m each)

  qs[t] = Qp[(size_t)n0 * 64 + t];
  __syncthreads();
  float Qreg[2][32];
#pragma unroll
  for (int j = 0; j < 2; j++)
#pragma unroll
    for (int dd = 0; dd < 32; dd++) Qreg[j][dd] = qs[(sqp * 2 + j) * 64 + shp * 32 + dd];

  // ---- pass 1: online max / sum-exp over m-tiles ----
  float M[2][2], Z[2][2];
#pragma unroll
  for (int j = 0; j < 2; j++)
#pragma unroll
    for (int hh = 0; hh < 2; hh++) { M[j][hh] = -3.0e38f; Z[j][hh] = 0.f; }

  for (int tile = 0; tile < 64; tile++) {
    // stage K tile (coalesced global, swizzled LDS)
#pragma unroll
    for (int jj = 0; jj < 4; jj++) {
      int flat = jj * 1024 + t * 4;
      int m = flat >> 6, c = (flat & 63) >> 2;
      f32x4 v = *(const f32x4*)(Kp + (size_t)(tile * 64 + m) * 64 + c * 4);
      int sc = (c + (m & 15) + 4 * (m >> 4)) & 15;
      *(f32x4*)&Kt[(m * 16 + sc) * 4] = v;
    }
    __syncthreads();
    float s[2][2] = {{0.f, 0.f}, {0.f, 0.f}};
#pragma unroll
    for (int ci = 0; ci < 8; ci++) {
      int c = shp * 8 + ci;
      int sc = (c + (sm & 15) + 4 * (sm >> 4)) & 15;
      f32x4 k4 = *(const f32x4*)&Kt[(sm * 16 + sc) * 4];
      int hh = ci >> 2;
#pragma unroll
      for (int j = 0; j < 2; j++)
#pragma unroll
        for (int e = 0; e < 4; e++)
          s[j][hh] = fmaf(Qreg[j][ci * 4 + e], k4[e], s[j][hh]);
    }
#pragma unroll
    for (int j = 0; j < 2; j++)
#pragma unroll
      for (int hh = 0; hh < 2; hh++) {
        float sv = s[j][hh] * 0.25f;
        if (sv > M[j][hh]) { Z[j][hh] = fmaf(Z[j][hh], expf(M[j][hh] - sv), 1.0f); M[j][hh] = sv; }
        else               Z[j][hh] += expf(sv - M[j][hh]);
      }
    __syncthreads();
  }
  // reduce partials (ascending m_local, deterministic)
  {
    float* redM = VT;
    float* redZ = VT + 16 * 64;
#pragma unroll
    for (int j = 0; j < 2; j++)
#pragma unroll
      for (int hh = 0; hh < 2; hh++) {
        int row = (sqp * 2 + j) * 4 + (shp * 2 + hh);
        redM[row * 64 + sm] = M[j][hh];
        redZ[row * 64 + sm] = Z[j][hh];
      }
    __syncthreads();
    if (t < 16) {
      const float* pm = &redM[t * 64];
      const float* pz = &redZ[t * 64];
      float Mv = -3.0e38f, Zv = 0.f;
      for (int i = 0; i < 64; i++) {
        float m_ = pm[i], z_ = pz[i];
        if (m_ > Mv) { Zv = fmaf(Zv, expf(Mv - m_), z_); Mv = m_; }
        else         Zv = fmaf(z_, expf(m_ - Mv), Zv);
      }
      sMZ[0][t >> 2][t & 3] = Mv;
      sMZ[1][t >> 2][t & 3] = Zv;
    }
    __syncthreads();
  }
  float Mh[2][2], iZ[2][2];
#pragma unroll
  for (int j = 0; j < 2; j++)
#pragma unroll
    for (int hh = 0; hh < 2; hh++) {
      Mh[j][hh] = sMZ[0][sqp * 2 + j][shp * 2 + hh];
      iZ[j][hh] = 1.0f / sMZ[1][sqp * 2 + j][shp * 2 + hh];
    }
  __syncthreads();

  // ---- pass 2: P tile + avg vals + PV accumulation ----
  float vals[64];          // avg-attn values for q_v at m = tile*64 + sm (may be scratch)
  float o4[4][4];          // PV accumulators [q][e]
#pragma unroll
  for (int q = 0; q < 4; q++)
#pragma unroll
    for (int e = 0; e < 4; e++) o4[q][e] = 0.f;

  for (int tile = 0; tile < 64; tile++) {
    // stage K (swizzled) + V (chunk-transposed)
#pragma unroll
    for (int jj = 0; jj < 4; jj++) {
      int flat = jj * 1024 + t * 4;
      int m = flat >> 6, c = (flat & 63) >> 2;
      f32x4 kv = *(const f32x4*)(Kp + (size_t)(tile * 64 + m) * 64 + c * 4);
      int sc = (c + (m & 15) + 4 * (m >> 4)) & 15;
      *(f32x4*)&Kt[(m * 16 + sc) * 4] = kv;
      f32x4 vv = *(const f32x4*)(Vp + (size_t)(tile * 64 + m) * 64 + c * 4);
      *(f32x4*)&VT[(c * 65 + m) * 4] = vv;
    }
    __syncthreads();
    // scores + normalized p -> Pt
    {
      float s[2][2] = {{0.f, 0.f}, {0.f, 0.f}};
#pragma unroll
      for (int ci = 0; ci < 8; ci++) {
        int c = shp * 8 + ci;
        int sc = (c + (sm & 15) + 4 * (sm >> 4)) & 15;
        f32x4 k4 = *(const f32x4*)&Kt[(sm * 16 + sc) * 4];
        int hh = ci >> 2;
#pragma unroll
        for (int j = 0; j < 2; j++)
#pragma unroll
          for (int e = 0; e < 4; e++)
            s[j][hh] = fmaf(Qreg[j][ci * 4 + e], k4[e], s[j][hh]);
      }
#pragma unroll
      for (int j = 0; j < 2; j++)
#pragma unroll
        for (int hh = 0; hh < 2; hh++) {
          float p = expf(s[j][hh] * 0.25f - Mh[j][hh]) * iZ[j][hh];
          Pt[((sqp * 2 + j) * 4 + (shp * 2 + hh)) * 68 + sm] = p;
        }
    }
    __syncthreads();
    // avg vals for selection (reads all 4 heads of q_v)
    vals[tile] = 0.25f * (Pt[(q_v * 4 + 0) * 68 + sm] + Pt[(q_v * 4 + 1) * 68 + sm] +
                          Pt[(q_v * 4 + 2) * 68 + sm] + Pt[(q_v * 4 + 3) * 68 + sm]);
    // PV: thread (dq, me) covers m = me*4 .. me*4+3
    {
      int m0 = me * 4;
      int h = dq >> 2;
      f32x4 p4[4];
#pragma unroll
      for (int q = 0; q < 4; q++)
        p4[q] = *(const f32x4*)&Pt[(q * 4 + h) * 68 + m0];
#pragma unroll
      for (int i = 0; i < 4; i++) {
        f32x4 v4 = *(const f32x4*)&VT[(dq * 65 + m0 + i) * 4];
#pragma unroll
        for (int q = 0; q < 4; q++)
#pragma unroll
          for (int e = 0; e < 4; e++)
            o4[q][e] = fmaf(p4[q][i], v4[e], o4[q][e]);
      }
    }
    __syncthreads();
  }

  // ---- PV cross-slice reduction (ascending me, deterministic) ----
  {
    float* Osh = Kt;   // 16*4*16*4 = 4096 floats
#pragma unroll
    for (int q = 0; q < 4; q++)
#pragma unroll
      for (int e = 0; e < 4; e++)
        Osh[((me * 4 + q) * 16 + dq) * 4 + e] = o4[q][e];
    __syncthreads();
    int q2 = t >> 6, d = t & 63;
    float acc = 0.f;
    for (int i = 0; i < 16; i++)
      acc += Osh[((i * 4 + q2) * 16 + (d >> 2)) * 4 + (d & 3)];
    ctx[(size_t)(n0 + q2) * 64 + d] = acc;
    __syncthreads();
  }

  // ---- per-row radix select (Threefry rank; ties -> lowest index) ----
  float* rowbuf = VT;   // 4096 floats
  for (int q = 0; q < 4; q++) {
    if (q_v == q) {
      for (int tile = 0; tile < 64; tile++) rowbuf[tile * 64 + sm] = vals[tile];
    }
    int n = n0 + q;
    if (t == 0) {
      unsigned a0, a1, b0, b1;
      tf2x32(0u, 42u, 0u, 2u, a0, a1);
      tf2x32(0u, 42u, 1u, 3u, b0, b1);
      unsigned o0, o1, bits;
      if (n < 2048) { tf2x32(a1, b1, (unsigned)n, (unsigned)(n + 2048), o0, o1); bits = o0; }
      else          { tf2x32(a1, b1, (unsigned)(n - 2048), (unsigned)n, o0, o1); bits = o1; }
      sh_r = (int)(bits & 1023u);
      sh_prefix = 0u;
    }
    __syncthreads();
    int r = sh_r;
    unsigned prefix = 0u;
    int cnt_eq = 0;
    for (int level = 0; level < 4; level++) {
      int shift = 24 - 8 * level;
      hist[t] = 0u;
      __syncthreads();
      for (int i = t; i < 4096; i += 256) {
        unsigned u = __float_as_uint(rowbuf[i]);
        bool ok = (level == 0) || ((u >> (shift + 8)) == (prefix >> (shift + 8)));
        if (ok) atomicAdd(&hist[(u >> shift) & 255u], 1u);
      }
      __syncthreads();
      for (int off = 1; off < 256; off <<= 1) {
        unsigned v = (t >= off) ? hist[t - off] : 0u;
        __syncthreads();
        hist[t] += v;
        __syncthreads();
      }
      unsigned cb = (t > 0) ? hist[t - 1] : 0u;
      unsigned ci = hist[t];
      if ((unsigned)r >= cb && (unsigned)r < ci) {
        sh_prefix = prefix | ((unsigned)t << shift);
        sh_r = r - (int)cb;
        sh_cnt = (int)(ci - cb);
      }
      __syncthreads();
      prefix = sh_prefix; r = sh_r; cnt_eq = sh_cnt;
      __syncthreads();
    }
    if (cnt_eq == 1) {
      for (int i = t; i < 4096; i += 256)
        if (__float_as_uint(rowbuf[i]) == prefix) sampled[n] = i;
    } else if (t == 0) {
      int c = 0;
      for (int i = 0; i < 4096; i++)
        if (__float_as_uint(rowbuf[i]) == prefix) { if (c == r) { sampled[n] = i; break; } c++; }
    }
    __syncthreads();
  }
}

// global_niches = ctx @ out_w^T + out_b  (f32)
__global__ void k_outproj(const float* __restrict__ ctx, const float* __restrict__ ow,
                          const float* __restrict__ ob, float* __restrict__ gni) {
  __shared__ float cx[64];
  int n = blockIdx.x, t = threadIdx.x;  // 64 threads
  cx[t] = ctx[(size_t)n * 64 + t];
  __syncthreads();
  float acc = 0.f;
#pragma unroll 8
  for (int j = 0; j < 64; j++) acc = fmaf(cx[j], ow[t * 64 + j], acc);
  gni[(size_t)n * 64 + t] = acc + ob[t];
}

// bilinear discriminator logits (pos & neg), f32 outputs
__global__ void k_logits(const float* __restrict__ local, const float* __restrict__ gni,
                         const int* __restrict__ sampled,
                         const float* __restrict__ bw, const float* __restrict__ bb,
                         float* __restrict__ outp, float* __restrict__ outn) {
  __shared__ float lv[64], gp[64], gn[64];
  int n = blockIdx.x, t = threadIdx.x;  // 64 threads
  int sm = sampled[n];
  lv[t] = local[(size_t)n * 64 + t];
  gp[t] = gni[(size_t)n * 64 + t];
  gn[t] = gni[(size_t)sm * 64 + t];
  __syncthreads();
  float tp = 0.f, tn = 0.f;
#pragma unroll 8
  for (int e = 0; e < 64; e++) {
    float w = bw[t * 64 + e];
    tp = fmaf(w, gp[e], tp);
    tn = fmaf(w, gn[e], tn);
  }
  float vp = lv[t] * tp, vn = lv[t] * tn;
  for (int off = 32; off; off >>= 1) {
    vp += __shfl_down(vp, off, 64);
    vn += __shfl_down(vn, off, 64);
  }
  if (t == 0) {
    outp[n] = vp + bb[0];
    outn[n] = vn + bb[0];
  }
}

// ---------------------------------------------------------------------------
extern "C" void kernel_launch(void* const* d_in, const int* in_sizes, int n_in,
                              void* d_out, int out_size, void* d_ws, size_t ws_size,
                              hipStream_t stream) {
  const float* x      = (const float*)d_in[0];
  const int*   edge   = (const int*)d_in[1];
  const int*   sub    = (const int*)d_in[2];
  const float* enc_w1 = (const float*)d_in[3];
  const float* enc_b1 = (const float*)d_in[4];
  const float* enc_w2 = (const float*)d_in[5];
  const float* enc_b2 = (const float*)d_in[6];
  const float* dec_w1 = (const float*)d_in[7];
  const float* dec_b1 = (const float*)d_in[8];
  const float* dec_w2 = (const float*)d_in[9];
  const float* dec_b2 = (const float*)d_in[10];
  const float* ain_w  = (const float*)d_in[11];
  const float* ain_b  = (const float*)d_in[12];
  const float* aout_w = (const float*)d_in[13];
  const float* aout_b = (const float*)d_in[14];
  const float* bil_w  = (const float*)d_in[15];
  const float* bil_b  = (const float*)d_in[16];
  float* out = (float*)d_out;

  const int E = in_sizes[1] / 2;  // 49152
  const int* esrc = edge;
  const int* edst = edge + E;

  // ---- time-overlapped workspace (~19.8 MB) ----
  char* base = (char*)d_ws;
  const size_t MB = (size_t)1 << 20;
  float*          cpart    = (float*)(base + 0);             // [conv1..combine] 16MB (2 x 8MB)
  float*          h_pre    = (float*)(base + 0);             // = cpart slice 0, [combine..agg1]
  unsigned short* dech_bf  = (unsigned short*)(base + 0);    // [dec1..dec2] 4MB
  float*          h        = (float*)(base + 8*MB);          // [agg1..mmw2] 8MB
  float*          Qp       = (float*)(base + 8*MB);          // [qkv..attn] 1MB
  float*          Kp       = (float*)(base + 9*MB);          // [qkv..attn] 1MB
  float*          Vp       = (float*)(base + 10*MB);         // [qkv..attn] 1MB
  float*          ctx      = (float*)(base + 11*MB);         // [attn..outproj] 1MB
  float*          gni      = (float*)(base + 12*MB);         // [outproj..logits] 1MB
  float*          hw2      = (float*)(base + 16*MB);         // [mmw2..agg2] 1MB
  float*          spot     = (float*)(base + 17*MB);         // [agg2..pool] 1MB
  float*          localf   = (float*)(base + 18*MB);         // [pool..logits] 1MB
  unsigned short* local_bf = (unsigned short*)(base + 19*MB);// [pool..dec1] 0.5MB
  char* ip = base + 19*MB + 512*1024;
  float* inv    = (float*)ip;  ip += 16384;
  int*   degcnt = (int*)ip;    ip += 16384;  // zeroed
  int*   cursor = (int*)ip;    ip += 16384;  // zeroed
  int*   offs   = (int*)ip;    ip += 16640;
  int*   sampled= (int*)ip;    ip += 16384;
  int*   eid    = (int*)ip;    ip += (size_t)E * 4;

  hipMemsetAsync(degcnt, 0, (size_t)NN * 4, stream);
  hipMemsetAsync(cursor, 0, (size_t)NN * 4, stream);

  int egrid = (E + 255) / 256;
  k_deg<<<egrid, 256, 0, stream>>>(edst, degcnt, E);
  k_inv<<<(NN + 255) / 256, 256, 0, stream>>>(degcnt, inv);
  k_scan<<<1, 1024, 0, stream>>>(degcnt, offs);
  k_scatter<<<egrid, 256, 0, stream>>>(edst, offs, cursor, eid, E);
  k_sort<<<(NN + 255) / 256, 256, 0, stream>>>(offs, eid);

  // encoder conv1: f32, split-K=2 + deterministic combine
  {
    dim3 g(4, 32, 2);
    k_gemm_f32<<<g, 256, 0, stream>>>(x, enc_w1, cpart);
  }
  k_combine<<<(NN * 512 / 4) / 256, 256, 0, stream>>>(h_pre, cpart + (size_t)NN * 512);
  k_agg<<<NN, 256, 0, stream>>>(h_pre, h, enc_b1, offs, eid, esrc, inv, 512, 1);
  k_mmw2<<<NN / 4, 256, 0, stream>>>(h, enc_w2, hw2);
  k_agg<<<NN, 256, 0, stream>>>(hw2, spot, enc_b2, offs, eid, esrc, inv, 64, 0);
  k_pool<<<NN, 64, 0, stream>>>(spot, sub, localf, local_bf);

  // decoder (bf16 MFMA, f32 weights converted on the fly)
  {
    dim3 g(4, 32);
    k_gemm_bf<<<g, 256, 0, stream>>>(local_bf, dec_w1, nullptr, dech_bf, dec_b1,
                                     NN, 512, 64, 512, 1);
  }
  {
    dim3 g(24, 32);
    k_gemm_bf<<<g, 256, 0, stream>>>(dech_bf, dec_w2, out, nullptr, dec_b2,
                                     NN, INDIM, 512, INDIM, 2);
  }

  // attention (f32 ranking path, fused stats+avg+ctx+select)
  k_qkv<<<NN, 192, 0, stream>>>(localf, ain_w, ain_b, Qp, Kp, Vp);
  k_attn<<<NN / RT, 256, 0, stream>>>(Qp, Kp, Vp, ctx, sampled);
  k_outproj<<<NN, 64, 0, stream>>>(ctx, aout_w, aout_b, gni);
  k_logits<<<NN, 64, 0, stream>>>(localf, gni, sampled, bil_w, bil_b,
                                  out + RECON_ELEMS, out + RECON_ELEMS + NN);
}

// Round 5
// 1371.328 us; speedup vs baseline: 1.7559x; 1.0723x over previous
//
#include <hip/hip_runtime.h>
#include <hip/hip_bf16.h>
#include <stdint.h>

// Problem constants (NicheST): N=4096, IN_DIM=3000, H1=512, D=64, K_sub=32, E=49152, HEADS=4
#define NN      4096
#define INDIM   3000
#define H1DIM   512
#define DDIM    64
#define RECON_ELEMS (NN * INDIM)

typedef __attribute__((ext_vector_type(8))) __bf16          bf16x8;
typedef __attribute__((ext_vector_type(8))) unsigned short  u16x8;
typedef __attribute__((ext_vector_type(4))) float           f32x4;

__device__ __forceinline__ unsigned short f2bf(float f) {
  union { float f; unsigned int i; } v; v.f = f;
  unsigned int x = v.i;
  unsigned int lsb = (x >> 16) & 1u;
  x += 0x7FFFu + lsb;                  // round-to-nearest-even
  return (unsigned short)(x >> 16);
}

// ---------------------------------------------------------------------------
// Threefry-2x32 (JAX-compatible, 20 rounds)
// ---------------------------------------------------------------------------
__device__ __forceinline__ void tf2x32(unsigned k0, unsigned k1, unsigned x0, unsigned x1,
                                       unsigned &o0, unsigned &o1) {
  unsigned ks2 = k0 ^ k1 ^ 0x1BD11BDAu;
  x0 += k0; x1 += k1;
#define TFR(r) { x0 += x1; x1 = (x1 << (r)) | (x1 >> (32 - (r))); x1 ^= x0; }
  TFR(13) TFR(15) TFR(26) TFR(6)
  x0 += k1; x1 += ks2 + 1u;
  TFR(17) TFR(29) TFR(16) TFR(24)
  x0 += ks2; x1 += k0 + 2u;
  TFR(13) TFR(15) TFR(26) TFR(6)
  x0 += k0; x1 += k1 + 3u;
  TFR(17) TFR(29) TFR(16) TFR(24)
  x0 += k1; x1 += ks2 + 4u;
  TFR(13) TFR(15) TFR(26) TFR(6)
  x0 += ks2; x1 += k0 + 5u;
#undef TFR
  o0 = x0; o1 = x1;
}

// ---------------------------------------------------------------------------
// Graph preprocessing
// ---------------------------------------------------------------------------
__global__ void k_deg(const int* __restrict__ dst, int* __restrict__ cnt, int E) {
  int e = blockIdx.x * 256 + threadIdx.x;
  if (e < E) atomicAdd(&cnt[dst[e]], 1);
}

__global__ void k_inv(const int* __restrict__ cnt, float* __restrict__ inv) {
  int n = blockIdx.x * 256 + threadIdx.x;
  if (n < NN) inv[n] = 1.0f / sqrtf((float)cnt[n] + 1.0f);
}

__global__ __launch_bounds__(1024) void k_scan(const int* __restrict__ cnt, int* __restrict__ offs) {
  __shared__ int ssum[1024];
  int tid = threadIdx.x;
  int c0 = cnt[tid*4], c1 = cnt[tid*4+1], c2 = cnt[tid*4+2], c3 = cnt[tid*4+3];
  int s = c0 + c1 + c2 + c3;
  ssum[tid] = s;
  __syncthreads();
  for (int off = 1; off < 1024; off <<= 1) {
    int v = (tid >= off) ? ssum[tid - off] : 0;
    __syncthreads();
    ssum[tid] += v;
    __syncthreads();
  }
  int base = ssum[tid] - s;  // exclusive prefix
  offs[tid*4]   = base;
  offs[tid*4+1] = base + c0;
  offs[tid*4+2] = base + c0 + c1;
  offs[tid*4+3] = base + c0 + c1 + c2;
  if (tid == 1023) offs[4096] = ssum[1023];
}

__global__ void k_scatter(const int* __restrict__ dst, const int* __restrict__ offs,
                          int* __restrict__ cur, int* __restrict__ eid, int E) {
  int e = blockIdx.x * 256 + threadIdx.x;
  if (e < E) {
    int d = dst[e];
    int pos = offs[d] + atomicAdd(&cur[d], 1);
    eid[pos] = e;
  }
}

// sort each node's edge list ascending by edge id -> deterministic accumulation
__global__ void k_sort(const int* __restrict__ offs, int* __restrict__ eid) {
  int n = blockIdx.x * 256 + threadIdx.x;
  if (n >= NN) return;
  int b = offs[n], e = offs[n+1];
  for (int i = b + 1; i < e; i++) {
    int v = eid[i]; int j = i - 1;
    while (j >= b && eid[j] > v) { eid[j+1] = eid[j]; j--; }
    eid[j+1] = v;
  }
}

// ---------------------------------------------------------------------------
// fp32 GEMM (conv1): C_z = x[4096,3000] @ w1[3000,512] over K-slice z.
// 128x128 tile, BK=16, 256 thr, 8x8/thread (2x2 blocks of 4x4). Split-K=2.
// ---------------------------------------------------------------------------
#define FBK 16
__global__ __launch_bounds__(256) void k_gemm_f32(
    const float* __restrict__ A, const float* __restrict__ B, float* __restrict__ C) {
  __shared__ float As[FBK * 132];
  __shared__ float Bs[FBK * 132];
  const int tid = threadIdx.x;
  const int m0 = blockIdx.y * 128;
  const int n0 = blockIdx.x * 128;
  const int z  = blockIdx.z;
  const int kBeg = z ? 1504 : 0;
  const int kEnd = z ? 3000 : 1504;
  C += (size_t)z * NN * 512;
  const int lane = tid & 63, w = tid >> 6;
  const int rg = w * 4 + (lane >> 4);  // 0..15 row group
  const int cg = lane & 15;            // 0..15 col group
  f32x4 acc[2][2][4];
#pragma unroll
  for (int a = 0; a < 2; a++)
#pragma unroll
    for (int b = 0; b < 2; b++)
#pragma unroll
      for (int i = 0; i < 4; i++) acc[a][b][i] = (f32x4){0.f,0.f,0.f,0.f};

  const int arow = tid & 127;
  const int asl  = tid >> 7;   // 0..1
  const int bkr  = tid >> 4;   // 0..15
  const int bcq  = tid & 15;   // 0..15

  for (int kt = kBeg; kt < kEnd; kt += FBK) {
    bool full = (kt + FBK <= kEnd);
    // stage A transposed: As[k][row]
#pragma unroll
    for (int it = 0; it < 2; it++) {
      int kk = (asl * 2 + it) * 4;
      f32x4 v;
      if (full) {
        v = *(const f32x4*)(A + (size_t)(m0 + arow) * INDIM + kt + kk);
      } else {
#pragma unroll
        for (int j = 0; j < 4; j++)
          v[j] = (kt + kk + j < kEnd) ? A[(size_t)(m0 + arow) * INDIM + kt + kk + j] : 0.f;
      }
      As[(kk+0)*132 + arow] = v[0];
      As[(kk+1)*132 + arow] = v[1];
      As[(kk+2)*132 + arow] = v[2];
      As[(kk+3)*132 + arow] = v[3];
    }
    // stage B: Bs[k][col]
    {
      f32x4 v0, v1;
      if (full || kt + bkr < kEnd) {
        const float* bp = B + (size_t)(kt + bkr) * 512 + n0 + bcq * 8;
        v0 = *(const f32x4*)bp;
        v1 = *(const f32x4*)(bp + 4);
      } else { v0 = (f32x4){0.f,0.f,0.f,0.f}; v1 = v0; }
      *(f32x4*)&Bs[bkr*132 + bcq*8]     = v0;
      *(f32x4*)&Bs[bkr*132 + bcq*8 + 4] = v1;
    }
    __syncthreads();
#pragma unroll
    for (int k = 0; k < FBK; k++) {
      f32x4 a0 = *(const f32x4*)&As[k*132 + rg*4];
      f32x4 a1 = *(const f32x4*)&As[k*132 + 64 + rg*4];
      f32x4 b0 = *(const f32x4*)&Bs[k*132 + cg*4];
      f32x4 b1 = *(const f32x4*)&Bs[k*132 + 64 + cg*4];
#pragma unroll
      for (int i = 0; i < 4; i++)
#pragma unroll
        for (int j = 0; j < 4; j++) {
          acc[0][0][i][j] = fmaf(a0[i], b0[j], acc[0][0][i][j]);
          acc[0][1][i][j] = fmaf(a0[i], b1[j], acc[0][1][i][j]);
          acc[1][0][i][j] = fmaf(a1[i], b0[j], acc[1][0][i][j]);
          acc[1][1][i][j] = fmaf(a1[i], b1[j], acc[1][1][i][j]);
        }
    }
    __syncthreads();
  }
#pragma unroll
  for (int a = 0; a < 2; a++)
#pragma unroll
    for (int i = 0; i < 4; i++) {
      int gr = m0 + a*64 + rg*4 + i;
#pragma unroll
      for (int b = 0; b < 2; b++)
        *(f32x4*)(C + (size_t)gr * 512 + n0 + b*64 + cg*4) = acc[a][b][i];
    }
}

// deterministic split-K combine: c0 += c1 (in place)
__global__ void k_combine(float* __restrict__ c0, const float* __restrict__ c1) {
  int i = blockIdx.x * 256 + threadIdx.x;
  ((f32x4*)c0)[i] = ((const f32x4*)c0)[i] + ((const f32x4*)c1)[i];
}

// ---------------------------------------------------------------------------
// bf16 MFMA GEMM (decoder): A bf16 [M,K], B f32 [K,N] converted on the fly.
// mode 1: +bias, ReLU, bf16 out. mode 2: +bias, f32 out.  K must be mult of 32.
// ---------------------------------------------------------------------------
__global__ __launch_bounds__(256) void k_gemm_bf(
    const unsigned short* __restrict__ A, const float* __restrict__ B,
    float* __restrict__ Cf, unsigned short* __restrict__ Cb,
    const float* __restrict__ bias,
    int M, int N, int K, int ldc, int mode) {
  __shared__ __attribute__((aligned(16))) unsigned short As[128 * 40];
  __shared__ __attribute__((aligned(16))) unsigned short Bs[128 * 40];
  const int tid  = threadIdx.x;
  const int m0   = blockIdx.y * 128;
  const int n0   = blockIdx.x * 128;
  const int lane = tid & 63;
  const int wid  = tid >> 6;
  const int wm   = wid >> 1, wn = wid & 1;
  const int lrow = lane & 15, lk = lane >> 4;

  f32x4 acc[4][4];
#pragma unroll
  for (int i = 0; i < 4; i++)
#pragma unroll
    for (int j = 0; j < 4; j++) acc[i][j] = (f32x4){0.f, 0.f, 0.f, 0.f};

  for (int k0 = 0; k0 < K; k0 += 32) {
    // stage A (already bf16)
#pragma unroll
    for (int it = 0; it < 2; it++) {
      int c   = it * 256 + tid;
      int row = c >> 2, kc = c & 3;
      int kg  = k0 + kc * 8;
      u16x8 v = *(const u16x8*)(A + (size_t)(m0 + row) * K + kg);
      *(u16x8*)&As[row * 40 + kc * 8] = v;
    }
    // stage B transposed, f32 -> bf16
    {
      int kk_ = tid & 31;
      int nc0 = tid >> 5;
      int kg  = k0 + kk_;
#pragma unroll
      for (int it = 0; it < 2; it++) {
        int nc = nc0 + it * 8;
        int ng = n0 + nc * 8;
        unsigned short vb[8];
        if (ng + 8 <= N) {
          f32x4 f0 = *(const f32x4*)(B + (size_t)kg * N + ng);
          f32x4 f1 = *(const f32x4*)(B + (size_t)kg * N + ng + 4);
#pragma unroll
          for (int j = 0; j < 4; j++) { vb[j] = f2bf(f0[j]); vb[4+j] = f2bf(f1[j]); }
        } else {
#pragma unroll
          for (int j = 0; j < 8; j++)
            vb[j] = (ng + j < N) ? f2bf(B[(size_t)kg * N + ng + j]) : (unsigned short)0;
        }
#pragma unroll
        for (int j = 0; j < 8; j++) Bs[(nc * 8 + j) * 40 + kk_] = vb[j];
      }
    }
    __syncthreads();
    bf16x8 af[4], bfr[4];
#pragma unroll
    for (int mi = 0; mi < 4; mi++) {
      u16x8 r = *(const u16x8*)&As[(wm * 64 + mi * 16 + lrow) * 40 + lk * 8];
      af[mi] = __builtin_bit_cast(bf16x8, r);
    }
#pragma unroll
    for (int ni = 0; ni < 4; ni++) {
      u16x8 r = *(const u16x8*)&Bs[(wn * 64 + ni * 16 + lrow) * 40 + lk * 8];
      bfr[ni] = __builtin_bit_cast(bf16x8, r);
    }
#pragma unroll
    for (int mi = 0; mi < 4; mi++)
#pragma unroll
      for (int ni = 0; ni < 4; ni++)
        acc[mi][ni] = __builtin_amdgcn_mfma_f32_16x16x32_bf16(af[mi], bfr[ni], acc[mi][ni], 0, 0, 0);
    __syncthreads();
  }

#pragma unroll
  for (int mi = 0; mi < 4; mi++)
#pragma unroll
    for (int ni = 0; ni < 4; ni++)
#pragma unroll
      for (int reg = 0; reg < 4; reg++) {
        int gr = m0 + wm * 64 + mi * 16 + lk * 4 + reg;
        int gc = n0 + wn * 64 + ni * 16 + lrow;
        if (gc < N) {
          float v = acc[mi][ni][reg] + bias[gc];
          if (mode == 1) {
            if (v < 0.f) v = 0.f;
            Cb[(size_t)gr * ldc + gc] = f2bf(v);
          } else {
            Cf[(size_t)gr * ldc + gc] = v;
          }
        }
      }
}

// ---------------------------------------------------------------------------
// GCN aggregation (deterministic edge order), f32
// ---------------------------------------------------------------------------
__global__ __launch_bounds__(256) void k_agg(
    const float* __restrict__ X, float* __restrict__ Y,
    const float* __restrict__ bias, const int* __restrict__ offs,
    const int* __restrict__ eid, const int* __restrict__ esrc,
    const float* __restrict__ inv, int F, int relu) {
  int n = blockIdx.x;
  int beg = offs[n], end = offs[n + 1];
  float invn = inv[n];
  float inv2 = invn * invn;
  for (int d = threadIdx.x; d < F; d += 256) {
    float acc = 0.f;
    for (int t = beg; t < end; t++) {
      int e = eid[t]; int s = esrc[e];
      float cf = inv[s] * invn;
      acc += X[(size_t)s * F + d] * cf;
    }
    acc += X[(size_t)n * F + d] * inv2;
    acc += bias[d];
    if (relu && acc < 0.f) acc = 0.f;
    Y[(size_t)n * F + d] = acc;
  }
}

// hw2[4096,64] = h[4096,512] @ enc_w2[512,64], all f32 (ranking path)
__global__ __launch_bounds__(256) void k_mmw2(const float* __restrict__ h,
                                              const float* __restrict__ w2,
                                              float* __restrict__ out) {
  __shared__ float hs[4 * 512];
  int tid  = threadIdx.x;
  int brow = blockIdx.x * 4;
  const f32x4* src = (const f32x4*)(h + (size_t)brow * 512);
  f32x4* dst4 = (f32x4*)hs;
  dst4[tid]       = src[tid];
  dst4[tid + 256] = src[tid + 256];
  __syncthreads();
  int r = tid >> 6, c = tid & 63;
  float acc = 0.f;
  const float* hr = hs + r * 512;
#pragma unroll 8
  for (int k = 0; k < 512; k++) acc = fmaf(hr[k], w2[k * 64 + c], acc);
  out[(size_t)(brow + r) * 64 + c] = acc;
}

// local[n] = mean over 32 sub_nodes of spot_emb (+ bf16 copy for decoder)
__global__ void k_pool(const float* __restrict__ spot, const int* __restrict__ sub,
                       float* __restrict__ local, unsigned short* __restrict__ local_bf) {
  int n = blockIdx.x, d = threadIdx.x;  // 64 threads
  float acc = 0.f;
  for (int j = 0; j < 32; j++) {
    int s = sub[n * 32 + j];
    acc += spot[(size_t)s * 64 + d];
  }
  float lv = acc * 0.03125f;
  local[(size_t)n * 64 + d] = lv;
  local_bf[(size_t)n * 64 + d] = f2bf(lv);
}

// Q/K/V packed rows: Qp/Kp/Vp[n][64] = local[n] @ in_w^T + in_b (f32)
__global__ void k_qkv(const float* __restrict__ local, const float* __restrict__ iw,
                      const float* __restrict__ ib,
                      float* __restrict__ Qp, float* __restrict__ Kp, float* __restrict__ Vp) {
  __shared__ float lx[64];
  int n = blockIdx.x, t = threadIdx.x;  // 192 threads
  if (t < 64) lx[t] = local[(size_t)n * 64 + t];
  __syncthreads();
  float acc = 0.f;
#pragma unroll 8
  for (int d = 0; d < 64; d++) acc = fmaf(lx[d], iw[t * 64 + d], acc);
  acc += ib[t];
  if (t < 64)       Qp[(size_t)n * 64 + t] = acc;
  else if (t < 128) Kp[(size_t)n * 64 + (t - 64)] = acc;
  else              Vp[(size_t)n * 64 + (t - 128)] = acc;
}

// ---------------------------------------------------------------------------
// Fused attention v3: 2048 blocks x 2 q-rows. Register-prefetched staging,
// avg rows kept in LDS (no scratch), wave-scan radix select.
// Thread roles: scores = (sm 0..63, sq 0..1, shp 0..1); PV = (dq 0..15, me 0..15).
// ---------------------------------------------------------------------------
#define RT 2
__global__ __launch_bounds__(256, 2) void k_attn(
    const float* __restrict__ Qp, const float* __restrict__ Kp, const float* __restrict__ Vp,
    float* __restrict__ ctx, int* __restrict__ sampled) {
  __shared__ __attribute__((aligned(16))) float regA[2][64 * 64]; // pass1: Kt dbuf; pass2+: rowbuf [2][4096]
  __shared__ __attribute__((aligned(16))) float KtB[64 * 64];     // pass2 K swizzled; epilogue: Osh
  __shared__ __attribute__((aligned(16))) float Vn[64 * 68];      // pass2 V padded; pass1: redM/redZ
  __shared__ __attribute__((aligned(16))) float Pt[8 * 68];
  __shared__ float qs[128];
  __shared__ float sMZ[2][2][4];   // [M/Z][q][h]
  __shared__ unsigned hist[256];
  __shared__ unsigned wtot[4];
  __shared__ unsigned sh_prefix;
  __shared__ int sh_r, sh_cnt;

  const int t   = threadIdx.x;
  const int n0  = blockIdx.x * RT;
  const int sm  = t & 63;
  const int sq  = (t >> 6) & 1;
  const int shp = t >> 7;
  const int dq  = t & 15;   // PV: d-quad
  const int me  = t >> 4;   // PV: m-slice
  const int stm = t >> 4;   // staging row within 16-group
  const int stc = t & 15;   // staging col quad

  if (t < 128) qs[t] = Qp[(size_t)n0 * 64 + t];
  __syncthreads();
  float Qreg[32];
#pragma unroll
  for (int dd = 0; dd < 32; dd++) Qreg[dd] = qs[sq * 64 + shp * 32 + dd];

  // ---- pass 1: online M, Z (Kt double-buffered in regA, 1 barrier/tile) ----
  f32x4 kreg[4];
#pragma unroll
  for (int jj = 0; jj < 4; jj++)
    kreg[jj] = *(const f32x4*)(Kp + (size_t)(jj * 16 + stm) * 64 + stc * 4);

  float M[2] = {-3.0e38f, -3.0e38f}, Z[2] = {0.f, 0.f};
  for (int tile = 0; tile < 64; tile++) {
    float* Kt = regA[tile & 1];
#pragma unroll
    for (int jj = 0; jj < 4; jj++) {
      int m = jj * 16 + stm;
      int sc = (stc + (m & 15) + 4 * (m >> 4)) & 15;
      *(f32x4*)&Kt[(m * 16 + sc) * 4] = kreg[jj];
    }
    __syncthreads();
    if (tile < 63) {
#pragma unroll
      for (int jj = 0; jj < 4; jj++)
        kreg[jj] = *(const f32x4*)(Kp + (size_t)((tile + 1) * 64 + jj * 16 + stm) * 64 + stc * 4);
    }
    float s[2] = {0.f, 0.f};
#pragma unroll
    for (int ci = 0; ci < 8; ci++) {
      int c = shp * 8 + ci;
      int sc = (c + (sm & 15) + 4 * (sm >> 4)) & 15;
      f32x4 k4 = *(const f32x4*)&Kt[(sm * 16 + sc) * 4];
      int hh = ci >> 2;
#pragma unroll
      for (int e = 0; e < 4; e++)
        s[hh] = fmaf(Qreg[ci * 4 + e], k4[e], s[hh]);
    }
#pragma unroll
    for (int hh = 0; hh < 2; hh++) {
      float sv = s[hh] * 0.25f;
      if (sv > M[hh]) { Z[hh] = fmaf(Z[hh], expf(M[hh] - sv), 1.0f); M[hh] = sv; }
      else            Z[hh] += expf(sv - M[hh]);
    }
  }
  // reduce M/Z across the 64 m-lanes (deterministic ascending order)
  {
    float* redM = Vn;
    float* redZ = Vn + 512;
    int row = sq * 4 + shp * 2;
    redM[(row + 0) * 64 + sm] = M[0];
    redM[(row + 1) * 64 + sm] = M[1];
    redZ[(row + 0) * 64 + sm] = Z[0];
    redZ[(row + 1) * 64 + sm] = Z[1];
    __syncthreads();
    if (t < 8) {
      const float* pm = &redM[t * 64];
      const float* pz = &redZ[t * 64];
      float Mv = -3.0e38f, Zv = 0.f;
      for (int i = 0; i < 64; i++) {
        float m_ = pm[i], z_ = pz[i];
        if (m_ > Mv) { Zv = fmaf(Zv, expf(Mv - m_), z_); Mv = m_; }
        else         Zv = fmaf(z_, expf(m_ - Mv), Zv);
      }
      sMZ[0][t >> 2][t & 3] = Mv;
      sMZ[1][t >> 2][t & 3] = Zv;
    }
    __syncthreads();
  }
  float Mh[2], iZ[2];
#pragma unroll
  for (int hh = 0; hh < 2; hh++) {
    Mh[hh] = sMZ[0][sq][shp * 2 + hh];
    iZ[hh] = 1.0f / sMZ[1][sq][shp * 2 + hh];
  }
  __syncthreads();   // Vn free for V staging

  // ---- pass 2: p -> Pt, avg -> rowbuf (LDS), PV accumulate ----
  f32x4 vreg[4];
#pragma unroll
  for (int jj = 0; jj < 4; jj++) {
    kreg[jj] = *(const f32x4*)(Kp + (size_t)(jj * 16 + stm) * 64 + stc * 4);
    vreg[jj] = *(const f32x4*)(Vp + (size_t)(jj * 16 + stm) * 64 + stc * 4);
  }
  float* rowavg = (float*)regA;   // [2][4096]
  float o4[2][4];
#pragma unroll
  for (int q = 0; q < 2; q++)
#pragma unroll
    for (int e = 0; e < 4; e++) o4[q][e] = 0.f;

  for (int tile = 0; tile < 64; tile++) {
#pragma unroll
    for (int jj = 0; jj < 4; jj++) {
      int m = jj * 16 + stm;
      int sc = (stc + (m & 15) + 4 * (m >> 4)) & 15;
      *(f32x4*)&KtB[(m * 16 + sc) * 4] = kreg[jj];
      *(f32x4*)&Vn[m * 68 + stc * 4] = vreg[jj];
    }
    __syncthreads();
    if (tile < 63) {
#pragma unroll
      for (int jj = 0; jj < 4; jj++) {
        kreg[jj] = *(const f32x4*)(Kp + (size_t)((tile + 1) * 64 + jj * 16 + stm) * 64 + stc * 4);
        vreg[jj] = *(const f32x4*)(Vp + (size_t)((tile + 1) * 64 + jj * 16 + stm) * 64 + stc * 4);
      }
    }
    {
      float s[2] = {0.f, 0.f};
#pragma unroll
      for (int ci = 0; ci < 8; ci++) {
        int c = shp * 8 + ci;
        int sc = (c + (sm & 15) + 4 * (sm >> 4)) & 15;
        f32x4 k4 = *(const f32x4*)&KtB[(sm * 16 + sc) * 4];
        int hh = ci >> 2;
#pragma unroll
        for (int e = 0; e < 4; e++)
          s[hh] = fmaf(Qreg[ci * 4 + e], k4[e], s[hh]);
      }
#pragma unroll
      for (int hh = 0; hh < 2; hh++) {
        float p = expf(s[hh] * 0.25f - Mh[hh]) * iZ[hh];
        Pt[(sq * 4 + shp * 2 + hh) * 68 + sm] = p;
      }
    }
    __syncthreads();
    if (t < 128)
      rowavg[sq * 4096 + tile * 64 + sm] =
          0.25f * (Pt[(sq * 4 + 0) * 68 + sm] + Pt[(sq * 4 + 1) * 68 + sm] +
                   Pt[(sq * 4 + 2) * 68 + sm] + Pt[(sq * 4 + 3) * 68 + sm]);
    {
      int h = dq >> 2;
      f32x4 p4[2];
#pragma unroll
      for (int q = 0; q < 2; q++)
        p4[q] = *(const f32x4*)&Pt[(q * 4 + h) * 68 + me * 4];
#pragma unroll
      for (int i = 0; i < 4; i++) {
        f32x4 v4 = *(const f32x4*)&Vn[(me * 4 + i) * 68 + dq * 4];
#pragma unroll
        for (int q = 0; q < 2; q++)
#pragma unroll
          for (int e = 0; e < 4; e++)
            o4[q][e] = fmaf(p4[q][i], v4[e], o4[q][e]);
      }
    }
    __syncthreads();
  }

  // ---- PV cross-slice reduction (deterministic) ----
  {
    float* Osh = KtB;
#pragma unroll
    for (int q = 0; q < 2; q++)
#pragma unroll
      for (int e = 0; e < 4; e++)
        Osh[((me * 2 + q) * 16 + dq) * 4 + e] = o4[q][e];
    __syncthreads();
    if (t < 128) {
      int q2 = t >> 6, d = t & 63;
      float acc = 0.f;
      for (int i = 0; i < 16; i++)
        acc += Osh[((i * 2 + q2) * 16 + (d >> 2)) * 4 + (d & 3)];
      ctx[(size_t)(n0 + q2) * 64 + d] = acc;
    }
    __syncthreads();
  }

  // ---- per-row radix select (Threefry rank; ties -> lowest index) ----
  float* rowbuf = (float*)regA;
  for (int q = 0; q < RT; q++) {
    const float* row = rowbuf + q * 4096;
    int n = n0 + q;
    if (t == 0) {
      unsigned a0, a1, b0, b1;
      tf2x32(0u, 42u, 0u, 2u, a0, a1);
      tf2x32(0u, 42u, 1u, 3u, b0, b1);
      unsigned o0, o1, bits;
      if (n < 2048) { tf2x32(a1, b1, (unsigned)n, (unsigned)(n + 2048), o0, o1); bits = o0; }
      else          { tf2x32(a1, b1, (unsigned)(n - 2048), (unsigned)n, o0, o1); bits = o1; }
      sh_r = (int)(bits & 1023u);
      sh_prefix = 0u;
    }
    __syncthreads();
    int r = sh_r;
    unsigned prefix = 0u;
    int cnt_eq = 0;
    for (int level = 0; level < 4; level++) {
      int shift = 24 - 8 * level;
      hist[t] = 0u;
      __syncthreads();
      for (int i = t; i < 4096; i += 256) {
        unsigned u = __float_as_uint(row[i]);
        bool ok = (level == 0) || ((u >> (shift + 8)) == (prefix >> (shift + 8)));
        if (ok) atomicAdd(&hist[(u >> shift) & 255u], 1u);
      }
      __syncthreads();
      unsigned own = hist[t];
      unsigned v = own;
      for (int off = 1; off < 64; off <<= 1) {
        unsigned u2 = __shfl_up(v, off, 64);
        if ((t & 63) >= off) v += u2;
      }
      if ((t & 63) == 63) wtot[t >> 6] = v;
      __syncthreads();
      unsigned basev = 0;
#pragma unroll
      for (int w = 0; w < 4; w++) if (w < (t >> 6)) basev += wtot[w];
      v += basev;
      unsigned cb = v - own;
      if ((unsigned)r >= cb && (unsigned)r < v) {
        sh_prefix = prefix | ((unsigned)t << shift);
        sh_r = r - (int)cb;
        sh_cnt = (int)(v - cb);
      }
      __syncthreads();
      prefix = sh_prefix; r = sh_r; cnt_eq = sh_cnt;
    }
    if (cnt_eq == 1) {
      for (int i = t; i < 4096; i += 256)
        if (__float_as_uint(row[i]) == prefix) sampled[n] = i;
    } else if (t == 0) {
      int c = 0;
      for (int i = 0; i < 4096; i++)
        if (__float_as_uint(row[i]) == prefix) { if (c == r) { sampled[n] = i; break; } c++; }
    }
    __syncthreads();
  }
}

// global_niches = ctx @ out_w^T + out_b  (f32)
__global__ void k_outproj(const float* __restrict__ ctx, const float* __restrict__ ow,
                          const float* __restrict__ ob, float* __restrict__ gni) {
  __shared__ float cx[64];
  int n = blockIdx.x, t = threadIdx.x;  // 64 threads
  cx[t] = ctx[(size_t)n * 64 + t];
  __syncthreads();
  float acc = 0.f;
#pragma unroll 8
  for (int j = 0; j < 64; j++) acc = fmaf(cx[j], ow[t * 64 + j], acc);
  gni[(size_t)n * 64 + t] = acc + ob[t];
}

// bilinear discriminator logits (pos & neg), f32 outputs
__global__ void k_logits(const float* __restrict__ local, const float* __restrict__ gni,
                         const int* __restrict__ sampled,
                         const float* __restrict__ bw, const float* __restrict__ bb,
                         float* __restrict__ outp, float* __restrict__ outn) {
  __shared__ float lv[64], gp[64], gn[64];
  int n = blockIdx.x, t = threadIdx.x;  // 64 threads
  int sm = sampled[n];
  lv[t] = local[(size_t)n * 64 + t];
  gp[t] = gni[(size_t)n * 64 + t];
  gn[t] = gni[(size_t)sm * 64 + t];
  __syncthreads();
  float tp = 0.f, tn = 0.f;
#pragma unroll 8
  for (int e = 0; e < 64; e++) {
    float w = bw[t * 64 + e];
    tp = fmaf(w, gp[e], tp);
    tn = fmaf(w, gn[e], tn);
  }
  float vp = lv[t] * tp, vn = lv[t] * tn;
  for (int off = 32; off; off >>= 1) {
    vp += __shfl_down(vp, off, 64);
    vn += __shfl_down(vn, off, 64);
  }
  if (t == 0) {
    outp[n] = vp + bb[0];
    outn[n] = vn + bb[0];
  }
}

// ---------------------------------------------------------------------------
extern "C" void kernel_launch(void* const* d_in, const int* in_sizes, int n_in,
                              void* d_out, int out_size, void* d_ws, size_t ws_size,
                              hipStream_t stream) {
  const float* x      = (const float*)d_in[0];
  const int*   edge   = (const int*)d_in[1];
  const int*   sub    = (const int*)d_in[2];
  const float* enc_w1 = (const float*)d_in[3];
  const float* enc_b1 = (const float*)d_in[4];
  const float* enc_w2 = (const float*)d_in[5];
  const float* enc_b2 = (const float*)d_in[6];
  const float* dec_w1 = (const float*)d_in[7];
  const float* dec_b1 = (const float*)d_in[8];
  const float* dec_w2 = (const float*)d_in[9];
  const float* dec_b2 = (const float*)d_in[10];
  const float* ain_w  = (const float*)d_in[11];
  const float* ain_b  = (const float*)d_in[12];
  const float* aout_w = (const float*)d_in[13];
  const float* aout_b = (const float*)d_in[14];
  const float* bil_w  = (const float*)d_in[15];
  const float* bil_b  = (const float*)d_in[16];
  float* out = (float*)d_out;

  const int E = in_sizes[1] / 2;  // 49152
  const int* esrc = edge;
  const int* edst = edge + E;

  // ---- time-overlapped workspace (~19.8 MB) ----
  char* base = (char*)d_ws;
  const size_t MB = (size_t)1 << 20;
  float*          cpart    = (float*)(base + 0);             // [conv1..combine] 16MB (2 x 8MB)
  float*          h_pre    = (float*)(base + 0);             // = cpart slice 0, [combine..agg1]
  unsigned short* dech_bf  = (unsigned short*)(base + 0);    // [dec1..dec2] 4MB
  float*          h        = (float*)(base + 8*MB);          // [agg1..mmw2] 8MB
  float*          Qp       = (float*)(base + 8*MB);          // [qkv..attn] 1MB
  float*          Kp       = (float*)(base + 9*MB);          // [qkv..attn] 1MB
  float*          Vp       = (float*)(base + 10*MB);         // [qkv..attn] 1MB
  float*          ctx      = (float*)(base + 11*MB);         // [attn..outproj] 1MB
  float*          gni      = (float*)(base + 12*MB);         // [outproj..logits] 1MB
  float*          hw2      = (float*)(base + 16*MB);         // [mmw2..agg2] 1MB
  float*          spot     = (float*)(base + 17*MB);         // [agg2..pool] 1MB
  float*          localf   = (float*)(base + 18*MB);         // [pool..logits] 1MB
  unsigned short* local_bf = (unsigned short*)(base + 19*MB);// [pool..dec1] 0.5MB
  char* ip = base + 19*MB + 512*1024;
  float* inv    = (float*)ip;  ip += 16384;
  int*   degcnt = (int*)ip;    ip += 16384;  // zeroed
  int*   cursor = (int*)ip;    ip += 16384;  // zeroed
  int*   offs   = (int*)ip;    ip += 16640;
  int*   sampled= (int*)ip;    ip += 16384;
  int*   eid    = (int*)ip;    ip += (size_t)E * 4;

  hipMemsetAsync(degcnt, 0, (size_t)NN * 4, stream);
  hipMemsetAsync(cursor, 0, (size_t)NN * 4, stream);

  int egrid = (E + 255) / 256;
  k_deg<<<egrid, 256, 0, stream>>>(edst, degcnt, E);
  k_inv<<<(NN + 255) / 256, 256, 0, stream>>>(degcnt, inv);
  k_scan<<<1, 1024, 0, stream>>>(degcnt, offs);
  k_scatter<<<egrid, 256, 0, stream>>>(edst, offs, cursor, eid, E);
  k_sort<<<(NN + 255) / 256, 256, 0, stream>>>(offs, eid);

  // encoder conv1: f32, split-K=2 + deterministic combine
  {
    dim3 g(4, 32, 2);
    k_gemm_f32<<<g, 256, 0, stream>>>(x, enc_w1, cpart);
  }
  k_combine<<<(NN * 512 / 4) / 256, 256, 0, stream>>>(h_pre, cpart + (size_t)NN * 512);
  k_agg<<<NN, 256, 0, stream>>>(h_pre, h, enc_b1, offs, eid, esrc, inv, 512, 1);
  k_mmw2<<<NN / 4, 256, 0, stream>>>(h, enc_w2, hw2);
  k_agg<<<NN, 256, 0, stream>>>(hw2, spot, enc_b2, offs, eid, esrc, inv, 64, 0);
  k_pool<<<NN, 64, 0, stream>>>(spot, sub, localf, local_bf);

  // decoder (bf16 MFMA, f32 weights converted on the fly)
  {
    dim3 g(4, 32);
    k_gemm_bf<<<g, 256, 0, stream>>>(local_bf, dec_w1, nullptr, dech_bf, dec_b1,
                                     NN, 512, 64, 512, 1);
  }
  {
    dim3 g(24, 32);
    k_gemm_bf<<<g, 256, 0, stream>>>(dech_bf, dec_w2, out, nullptr, dec_b2,
                                     NN, INDIM, 512, INDIM, 2);
  }

  // attention (f32 ranking path, fused stats+avg+ctx+select)
  k_qkv<<<NN, 192, 0, stream>>>(localf, ain_w, ain_b, Qp, Kp, Vp);
  k_attn<<<NN / RT, 256, 0, stream>>>(Qp, Kp, Vp, ctx, sampled);
  k_outproj<<<NN, 64, 0, stream>>>(ctx, aout_w, aout_b, gni);
  k_logits<<<NN, 64, 0, stream>>>(localf, gni, sampled, bil_w, bil_b,
                                  out + RECON_ELEMS, out + RECON_ELEMS + NN);
}